// Round 1
// baseline (1523.872 us; speedup 1.0000x reference)
//
#include <hip/hip_runtime.h>
#include <math.h>

#define NPTS 1024
#define DIM 32
#define NWW 4
#define NPAIR 16   // B * NW = 4*4

// ---------------- build X: X[bw][n][d] = pc[b][n][d] * alphas[w][d] ----------------
__global__ __launch_bounds__(256) void build_X(const float* __restrict__ pc,
                                               const float* __restrict__ alphas,
                                               float* __restrict__ X) {
    int idx = blockIdx.x * 256 + threadIdx.x;      // over NPAIR*NPTS*DIM = 524288
    int d  = idx & (DIM - 1);
    int n  = (idx >> 5) & (NPTS - 1);
    int bw = idx >> 15;                            // / (NPTS*DIM)
    int b = bw >> 2, w = bw & 3;
    X[idx] = pc[(b * NPTS + n) * DIM + d] * alphas[w * DIM + d];
}

// ---------------- build P: P = 0.5*(I + W/deg), W = K * (K >= 0.5) ----------------
// grid (NPTS/8, NPAIR), block 1024. Thread j holds X_j in regs; 8 rows per block.
__global__ __launch_bounds__(1024) void build_P(const float* __restrict__ X,
                                                const float* __restrict__ sigp,
                                                float* __restrict__ P) {
    int pair = blockIdx.y;
    int i0 = blockIdx.x * 8;
    int j = threadIdx.x;
    float sigma = *sigp;
    const float* Xp = X + (size_t)pair * NPTS * DIM;

    float xj[DIM];
#pragma unroll
    for (int d = 0; d < DIM; d++) xj[d] = Xp[j * DIM + d];
    float sqj = 0.0f;
#pragma unroll
    for (int d = 0; d < DIM; d++) sqj += xj[d] * xj[d];

    __shared__ float wsum[16];
    int lane = threadIdx.x & 63, wave = threadIdx.x >> 6;

    for (int r = 0; r < 8; r++) {
        int i = i0 + r;
        const float* xi = Xp + i * DIM;
        float dot = 0.0f, sqi = 0.0f;
#pragma unroll
        for (int d = 0; d < DIM; d++) {
            float v = xi[d];            // uniform address -> scalar loads
            dot += v * xj[d];
            sqi += v * v;
        }
        float Dm = sqi + sqj - 2.0f * dot;
        float K = expf(-Dm / sigma);
        float Wv = (K >= 0.5f) ? K : 0.0f;

        // block reduction of Wv -> deg
        float s = Wv;
#pragma unroll
        for (int o = 32; o > 0; o >>= 1) s += __shfl_down(s, o);
        if (lane == 0) wsum[wave] = s;
        __syncthreads();
        float deg = 0.0f;
#pragma unroll
        for (int t = 0; t < 16; t++) deg += wsum[t];

        float Pv = 0.5f * Wv / deg + ((i == j) ? 0.5f : 0.0f);
        P[((size_t)pair * NPTS + i) * NPTS + j] = Pv;
        __syncthreads();   // wsum reused next row
    }
}

// ---------------- apply: O = P @ Y, per pair. DC in {32,64} ----------------
// BM=64 rows, BK=32. Threads: 16 row-groups x (DC/4) col-groups, micro-tile 4x4.
template <int DC>
__global__ __launch_bounds__(16 * (DC / 4)) void apply_P(const float* __restrict__ P,
                                                         const float* __restrict__ Y,
                                                         float* __restrict__ O) {
    constexpr int BM = 64, BK = 32;
    constexpr int NT = 16 * (DC / 4);
    int pair = blockIdx.y;
    int row0 = blockIdx.x * BM;
    const float* Pp = P + (size_t)pair * NPTS * NPTS;
    const float* Yp = Y + (size_t)pair * NPTS * DC;
    float* Op       = O + (size_t)pair * NPTS * DC;

    __shared__ float Pt[BK][BM];   // transposed: Pt[k][m] = P[row0+m][k0+k]
    __shared__ float Yt[BK][DC];

    int tid = threadIdx.x;
    int tx = tid & 15;         // row group (4 rows)
    int ty = tid >> 4;         // col group (4 cols)

    float acc[4][4] = {};

    for (int k0 = 0; k0 < NPTS; k0 += BK) {
        // load P tile (BM x BK), store transposed
        for (int t = tid; t < BM * BK / 4; t += NT) {
            int r  = t / (BK / 4);
            int kk = (t % (BK / 4)) * 4;
            float4 v = *(const float4*)&Pp[(size_t)(row0 + r) * NPTS + k0 + kk];
            Pt[kk + 0][r] = v.x; Pt[kk + 1][r] = v.y;
            Pt[kk + 2][r] = v.z; Pt[kk + 3][r] = v.w;
        }
        // load Y tile (BK x DC)
        for (int t = tid; t < BK * DC / 4; t += NT) {
            int kk = t / (DC / 4);
            int dd = (t % (DC / 4)) * 4;
            *(float4*)&Yt[kk][dd] = *(const float4*)&Yp[(size_t)(k0 + kk) * DC + dd];
        }
        __syncthreads();
#pragma unroll
        for (int k = 0; k < BK; k++) {
            float4 a = *(const float4*)&Pt[k][tx * 4];
            float4 b = *(const float4*)&Yt[k][ty * 4];
            acc[0][0] += a.x * b.x; acc[0][1] += a.x * b.y; acc[0][2] += a.x * b.z; acc[0][3] += a.x * b.w;
            acc[1][0] += a.y * b.x; acc[1][1] += a.y * b.y; acc[1][2] += a.y * b.z; acc[1][3] += a.y * b.w;
            acc[2][0] += a.z * b.x; acc[2][1] += a.z * b.y; acc[2][2] += a.z * b.z; acc[2][3] += a.z * b.w;
            acc[3][0] += a.w * b.x; acc[3][1] += a.w * b.y; acc[3][2] += a.w * b.z; acc[3][3] += a.w * b.w;
        }
        __syncthreads();
    }
#pragma unroll
    for (int i = 0; i < 4; i++) {
        int r = row0 + tx * 4 + i;
        float4 v = make_float4(acc[i][0], acc[i][1], acc[i][2], acc[i][3]);
        *(float4*)&Op[(size_t)r * DC + ty * 4] = v;
    }
}

// ---------------- Z0 = [ |T1-T2| , |T2-T4| ]  (D=64 concat) ----------------
__global__ __launch_bounds__(256) void build_Z0(const float* __restrict__ T1,
                                                const float* __restrict__ T2,
                                                const float* __restrict__ T4,
                                                float* __restrict__ Z0) {
    int idx = blockIdx.x * 256 + threadIdx.x;   // NPAIR*NPTS*DIM
    int d  = idx & 31;
    int bn = idx >> 5;                          // pair*NPTS + n
    Z0[(size_t)bn * 64 + d]      = fabsf(T1[idx] - T2[idx]);
    Z0[(size_t)bn * 64 + 32 + d] = fabsf(T2[idx] - T4[idx]);
}

// ---------------- pooling: mean over n of the 7 feature groups ----------------
// grid (7, NPAIR), block (32, 8)
__global__ __launch_bounds__(256) void pool_kernel(const float* __restrict__ X,
                                                   const float* __restrict__ Z0,
                                                   const float* __restrict__ T4,
                                                   const float* __restrict__ T8,
                                                   const float* __restrict__ Z2,
                                                   const float* __restrict__ Z4,
                                                   const float* __restrict__ Z8,
                                                   float* __restrict__ out) {
    int g = blockIdx.x;        // feature group 0..6
    int pair = blockIdx.y;
    int d = threadIdx.x;       // 0..31
    int ty = threadIdx.y;      // 0..7
    float s = 0.0f;
    for (int n = ty; n < NPTS; n += 8) {
        size_t i32 = ((size_t)pair * NPTS + n) * DIM + d;
        size_t i64 = ((size_t)pair * NPTS + n) * 64 + d;
        float v = 0.0f;
        switch (g) {
            case 0: v = X[i32]; break;
            case 1: v = Z0[i64]; break;                       // f0
            case 2: v = Z0[i64 + 32]; break;                  // f1
            case 3: v = fabsf(T4[i32] - T8[i32]); break;      // f2
            case 4: v = fabsf(Z2[i64] - Z4[i64]); break;      // s01
            case 5: v = fabsf(Z4[i64] - Z8[i64]); break;      // s02
            case 6: v = fabsf(Z4[i64 + 32] - Z8[i64 + 32]); break; // s12
        }
        s += v;
    }
    __shared__ float red[8][33];
    red[ty][d] = s;
    __syncthreads();
    if (ty == 0) {
        float tot = 0.0f;
#pragma unroll
        for (int t = 0; t < 8; t++) tot += red[t][d];
        out[(size_t)pair * 224 + g * 32 + d] = tot * (1.0f / 1024.0f);
    }
}

extern "C" void kernel_launch(void* const* d_in, const int* in_sizes, int n_in,
                              void* d_out, int out_size, void* d_ws, size_t ws_size,
                              hipStream_t stream) {
    const float* pc     = (const float*)d_in[0];  // [4,1024,32]
    const float* alphas = (const float*)d_in[1];  // [4,32]
    const float* sigp   = (const float*)d_in[2];  // scalar
    float* out = (float*)d_out;                   // [4, 896] fp32
    float* ws = (float*)d_ws;

    const size_t SZ32 = (size_t)NPAIR * NPTS * DIM;   // 524288 floats
    const size_t SZ64 = (size_t)NPAIR * NPTS * 64;    // 1048576 floats

    // workspace layout (floats):
    float* X  = ws;                                   // SZ32
    float* P  = X + SZ32;                             // NPAIR*NPTS*NPTS = 16777216
    float* T  = P + (size_t)NPAIR * NPTS * NPTS;      // T[1..8], 8*SZ32 (T[k] = Tbase + (k-1)*SZ32)
    float* Z  = T + 8 * SZ32;                         // Z[0..8], 9*SZ64
    // total ≈ 30.9M floats ≈ 124 MB

    auto Tk = [&](int k) { return T + (size_t)(k - 1) * SZ32; };
    auto Zk = [&](int k) { return Z + (size_t)k * SZ64; };

    build_X<<<dim3(SZ32 / 256), dim3(256), 0, stream>>>(pc, alphas, X);
    build_P<<<dim3(NPTS / 8, NPAIR), dim3(1024), 0, stream>>>(X, sigp, P);

    // Stage 1: T_k = P^k X, D=32
    {
        const float* src = X;
        for (int k = 1; k <= 8; k++) {
            apply_P<32><<<dim3(NPTS / 64, NPAIR), dim3(128), 0, stream>>>(P, src, Tk(k));
            src = Tk(k);
        }
    }

    // Z0 = [|T1-T2| , |T2-T4|]
    build_Z0<<<dim3(SZ32 / 256), dim3(256), 0, stream>>>(Tk(1), Tk(2), Tk(4), Zk(0));

    // Stage 2: Z_k = P^k Z0, D=64
    {
        const float* src = Zk(0);
        for (int k = 1; k <= 8; k++) {
            apply_P<64><<<dim3(NPTS / 64, NPAIR), dim3(256), 0, stream>>>(P, src, Zk(k));
            src = Zk(k);
        }
    }

    pool_kernel<<<dim3(7, NPAIR), dim3(32, 8), 0, stream>>>(X, Zk(0), Tk(4), Tk(8),
                                                            Zk(2), Zk(4), Zk(8), out);
}

// Round 2
// 788.769 us; speedup vs baseline: 1.9320x; 1.9320x over previous
//
#include <hip/hip_runtime.h>
#include <math.h>

#define NPTS 1024
#define DIM 32
#define NPAIR 16   // B*NW

// ============ build X + per-row squared norms ============
__global__ __launch_bounds__(256) void build_X(const float* __restrict__ pc,
                                               const float* __restrict__ alphas,
                                               float* __restrict__ X,
                                               float* __restrict__ sqX) {
    int idx = blockIdx.x * 256 + threadIdx.x;      // NPAIR*NPTS*DIM
    int d  = idx & 31;
    int n  = (idx >> 5) & 1023;
    int bw = idx >> 15;
    int b = bw >> 2, w = bw & 3;
    float v = pc[(b * NPTS + n) * DIM + d] * alphas[w * DIM + d];
    X[idx] = v;
    float s = v * v;
    s += __shfl_down(s, 16, 32);
    s += __shfl_down(s, 8, 32);
    s += __shfl_down(s, 4, 32);
    s += __shfl_down(s, 2, 32);
    s += __shfl_down(s, 1, 32);
    if (d == 0) sqX[bw * NPTS + n] = s;
}

// ============ pass 1: deg[i] = sum_j W_ij ============
// grid (16 rowtiles, NPAIR), block 256. 4x4 microtile, 64x64 j-tiles.
__global__ __launch_bounds__(256) void deg_kernel(const float* __restrict__ X,
                                                  const float* __restrict__ sqX,
                                                  const float* __restrict__ sigp,
                                                  float* __restrict__ deg) {
    int pair = blockIdx.y;
    int i0 = blockIdx.x * 64;
    float rsig = -1.0f / (*sigp);
    const float* Xp = X + (size_t)pair * NPTS * DIM;

    __shared__ float XiT[DIM][68];
    __shared__ float XjT[DIM][68];
    __shared__ float sqiS[64], sqjS[64];
    __shared__ float degred[16][64];

    int tid = threadIdx.x;
    int cx = tid & 15, ry = tid >> 4;

    for (int t = tid; t < 512; t += 256) {
        int r = t >> 3, dg = (t & 7) * 4;
        float4 v = *(const float4*)&Xp[(size_t)(i0 + r) * DIM + dg];
        XiT[dg][r] = v.x; XiT[dg + 1][r] = v.y; XiT[dg + 2][r] = v.z; XiT[dg + 3][r] = v.w;
    }
    if (tid < 64) sqiS[tid] = sqX[pair * NPTS + i0 + tid];

    float rs[4] = {0.f, 0.f, 0.f, 0.f};
    for (int jt = 0; jt < NPTS; jt += 64) {
        __syncthreads();
        for (int t = tid; t < 512; t += 256) {
            int r = t >> 3, dg = (t & 7) * 4;
            float4 v = *(const float4*)&Xp[(size_t)(jt + r) * DIM + dg];
            XjT[dg][r] = v.x; XjT[dg + 1][r] = v.y; XjT[dg + 2][r] = v.z; XjT[dg + 3][r] = v.w;
        }
        if (tid < 64) sqjS[tid] = sqX[pair * NPTS + jt + tid];
        __syncthreads();

        float dot[4][4] = {};
#pragma unroll
        for (int d = 0; d < DIM; d++) {
            float4 a = *(const float4*)&XiT[d][ry * 4];
            float4 b = *(const float4*)&XjT[d][cx * 4];
            dot[0][0] += a.x * b.x; dot[0][1] += a.x * b.y; dot[0][2] += a.x * b.z; dot[0][3] += a.x * b.w;
            dot[1][0] += a.y * b.x; dot[1][1] += a.y * b.y; dot[1][2] += a.y * b.z; dot[1][3] += a.y * b.w;
            dot[2][0] += a.z * b.x; dot[2][1] += a.z * b.y; dot[2][2] += a.z * b.z; dot[2][3] += a.z * b.w;
            dot[3][0] += a.w * b.x; dot[3][1] += a.w * b.y; dot[3][2] += a.w * b.z; dot[3][3] += a.w * b.w;
        }
#pragma unroll
        for (int a = 0; a < 4; a++) {
            float sqi = sqiS[ry * 4 + a];
#pragma unroll
            for (int b = 0; b < 4; b++) {
                float Dm = sqi + sqjS[cx * 4 + b] - 2.0f * dot[a][b];
                float K = __expf(Dm * rsig);
                rs[a] += (K >= 0.5f) ? K : 0.0f;
            }
        }
    }
    __syncthreads();
#pragma unroll
    for (int a = 0; a < 4; a++) degred[cx][ry * 4 + a] = rs[a];
    __syncthreads();
    if (tid < 64) {
        float s = 0.f;
#pragma unroll
        for (int c = 0; c < 16; c++) s += degred[c][tid];
        deg[pair * NPTS + i0 + tid] = s;
    }
}

// ============ pass 2: P = 0.5*(I + W/deg) ============
__global__ __launch_bounds__(256) void P_kernel(const float* __restrict__ X,
                                                const float* __restrict__ sqX,
                                                const float* __restrict__ sigp,
                                                const float* __restrict__ deg,
                                                float* __restrict__ P) {
    int pair = blockIdx.y;
    int i0 = blockIdx.x * 64;
    float rsig = -1.0f / (*sigp);
    const float* Xp = X + (size_t)pair * NPTS * DIM;
    float* Pp = P + (size_t)pair * NPTS * NPTS;

    __shared__ float XiT[DIM][68];
    __shared__ float XjT[DIM][68];
    __shared__ float sqiS[64], sqjS[64];

    int tid = threadIdx.x;
    int cx = tid & 15, ry = tid >> 4;

    for (int t = tid; t < 512; t += 256) {
        int r = t >> 3, dg = (t & 7) * 4;
        float4 v = *(const float4*)&Xp[(size_t)(i0 + r) * DIM + dg];
        XiT[dg][r] = v.x; XiT[dg + 1][r] = v.y; XiT[dg + 2][r] = v.z; XiT[dg + 3][r] = v.w;
    }
    if (tid < 64) sqiS[tid] = sqX[pair * NPTS + i0 + tid];

    float rdeg[4];
#pragma unroll
    for (int a = 0; a < 4; a++) rdeg[a] = 0.5f / deg[pair * NPTS + i0 + ry * 4 + a];

    for (int jt = 0; jt < NPTS; jt += 64) {
        __syncthreads();
        for (int t = tid; t < 512; t += 256) {
            int r = t >> 3, dg = (t & 7) * 4;
            float4 v = *(const float4*)&Xp[(size_t)(jt + r) * DIM + dg];
            XjT[dg][r] = v.x; XjT[dg + 1][r] = v.y; XjT[dg + 2][r] = v.z; XjT[dg + 3][r] = v.w;
        }
        if (tid < 64) sqjS[tid] = sqX[pair * NPTS + jt + tid];
        __syncthreads();

        float dot[4][4] = {};
#pragma unroll
        for (int d = 0; d < DIM; d++) {
            float4 a = *(const float4*)&XiT[d][ry * 4];
            float4 b = *(const float4*)&XjT[d][cx * 4];
            dot[0][0] += a.x * b.x; dot[0][1] += a.x * b.y; dot[0][2] += a.x * b.z; dot[0][3] += a.x * b.w;
            dot[1][0] += a.y * b.x; dot[1][1] += a.y * b.y; dot[1][2] += a.y * b.z; dot[1][3] += a.y * b.w;
            dot[2][0] += a.z * b.x; dot[2][1] += a.z * b.y; dot[2][2] += a.z * b.z; dot[2][3] += a.z * b.w;
            dot[3][0] += a.w * b.x; dot[3][1] += a.w * b.y; dot[3][2] += a.w * b.z; dot[3][3] += a.w * b.w;
        }
#pragma unroll
        for (int a = 0; a < 4; a++) {
            int i = i0 + ry * 4 + a;
            float sqi = sqiS[ry * 4 + a];
            float o[4];
#pragma unroll
            for (int b = 0; b < 4; b++) {
                int j = jt + cx * 4 + b;
                float Dm = sqi + sqjS[cx * 4 + b] - 2.0f * dot[a][b];
                float K = __expf(Dm * rsig);
                float W = (K >= 0.5f) ? K : 0.0f;
                o[b] = W * rdeg[a] + ((i == j) ? 0.5f : 0.0f);
            }
            *(float4*)&Pp[(size_t)i * NPTS + jt + cx * 4] = make_float4(o[0], o[1], o[2], o[3]);
        }
    }
}

// ============ split-K apply: Opart[slice] = P[:, slice] @ Y[slice, :] ============
// grid (16 rowtiles, KSPLIT, NPAIR), block 16*(DC/4). 4x4 microtile.
template <int DC, int KSPLIT>
__global__ __launch_bounds__(16 * (DC / 4)) void apply_partial(const float* __restrict__ P,
                                                               const float* __restrict__ Y,
                                                               float* __restrict__ Opart,
                                                               int srcStride, int srcOff) {
    constexpr int BM = 64, BK = 32, NCG = DC / 4, NT = 16 * NCG, KS = NPTS / KSPLIT;
    int pair = blockIdx.z, slice = blockIdx.y;
    int r0 = blockIdx.x * BM;
    int k0 = slice * KS;
    const float* Pp = P + (size_t)pair * NPTS * NPTS;
    const float* Yp = Y + (size_t)pair * NPTS * srcStride + srcOff;
    float* Op = Opart + ((size_t)slice * NPAIR + pair) * NPTS * DC;

    __shared__ float Pt[BK][68];
    __shared__ float Yt[BK][DC];

    int tid = threadIdx.x;
    int cx = tid % NCG, ry = tid / NCG;

    float acc[4][4] = {};
    for (int kt = 0; kt < KS; kt += BK) {
        int kb = k0 + kt;
        for (int t = tid; t < BM * BK / 4; t += NT) {
            int r = t >> 3, kk = (t & 7) * 4;
            float4 v = *(const float4*)&Pp[(size_t)(r0 + r) * NPTS + kb + kk];
            Pt[kk][r] = v.x; Pt[kk + 1][r] = v.y; Pt[kk + 2][r] = v.z; Pt[kk + 3][r] = v.w;
        }
        for (int t = tid; t < BK * DC / 4; t += NT) {
            int kk = t / NCG, dd = (t % NCG) * 4;
            *(float4*)&Yt[kk][dd] = *(const float4*)&Yp[(size_t)(kb + kk) * srcStride + dd];
        }
        __syncthreads();
#pragma unroll
        for (int k = 0; k < BK; k++) {
            float4 a = *(const float4*)&Pt[k][ry * 4];
            float4 b = *(const float4*)&Yt[k][cx * 4];
            acc[0][0] += a.x * b.x; acc[0][1] += a.x * b.y; acc[0][2] += a.x * b.z; acc[0][3] += a.x * b.w;
            acc[1][0] += a.y * b.x; acc[1][1] += a.y * b.y; acc[1][2] += a.y * b.z; acc[1][3] += a.y * b.w;
            acc[2][0] += a.z * b.x; acc[2][1] += a.z * b.y; acc[2][2] += a.z * b.z; acc[2][3] += a.z * b.w;
            acc[3][0] += a.w * b.x; acc[3][1] += a.w * b.y; acc[3][2] += a.w * b.z; acc[3][3] += a.w * b.w;
        }
        __syncthreads();
    }
#pragma unroll
    for (int a = 0; a < 4; a++) {
        *(float4*)&Op[(size_t)(r0 + ry * 4 + a) * DC + cx * 4] =
            make_float4(acc[a][0], acc[a][1], acc[a][2], acc[a][3]);
    }
}

// ============ reduce partials -> (possibly strided) dst ============
template <int DC, int NS>
__global__ __launch_bounds__(256) void reduce_partial(const float* __restrict__ Opart,
                                                      float* __restrict__ dst,
                                                      int dstStride, int dstOff) {
    constexpr int SLICE = NPAIR * NPTS * DC;
    int idx = blockIdx.x * 256 + threadIdx.x;     // over SLICE/4
    int e4 = idx * 4;
    float4 s = *(const float4*)&Opart[e4];
#pragma unroll
    for (int i = 1; i < NS; i++) {
        float4 v = *(const float4*)&Opart[(size_t)i * SLICE + e4];
        s.x += v.x; s.y += v.y; s.z += v.z; s.w += v.w;
    }
    int pn = e4 / DC, c = e4 % DC;
    *(float4*)&dst[(size_t)pn * dstStride + dstOff + c] = s;
}

// ============ M0 cols 32..95 = [ |A1-A2| , |A2-A4| ]  (A4 already in cols 0..31) ============
__global__ __launch_bounds__(256) void build_M0(const float* __restrict__ A1,
                                                const float* __restrict__ A2,
                                                float* __restrict__ M0) {
    int idx = blockIdx.x * 256 + threadIdx.x;   // NPAIR*NPTS*DIM
    int d = idx & 31;
    int pn = idx >> 5;
    float a1 = A1[idx], a2 = A2[idx];
    float a4 = M0[(size_t)pn * 96 + d];
    M0[(size_t)pn * 96 + 32 + d] = fabsf(a1 - a2);
    M0[(size_t)pn * 96 + 64 + d] = fabsf(a2 - a4);
}

// ============ pooling ============
// grid (7, NPAIR), block (32, 8)
__global__ __launch_bounds__(256) void pool_kernel(const float* __restrict__ X,
                                                   const float* __restrict__ M0,
                                                   const float* __restrict__ M2,
                                                   const float* __restrict__ M4,
                                                   const float* __restrict__ Z8,
                                                   float* __restrict__ out) {
    int g = blockIdx.x;
    int pair = blockIdx.y;
    int d = threadIdx.x;
    int ty = threadIdx.y;
    float s = 0.0f;
    for (int n = ty; n < NPTS; n += 8) {
        size_t pn = (size_t)pair * NPTS + n;
        float v = 0.0f;
        switch (g) {
            case 0: v = X[pn * 32 + d]; break;
            case 1: v = M0[pn * 96 + 32 + d]; break;                       // f0
            case 2: v = M0[pn * 96 + 64 + d]; break;                       // f1
            case 3: v = fabsf(M0[pn * 96 + d] - M4[pn * 96 + d]); break;   // f2 = |T4-T8|
            case 4: v = fabsf(M2[pn * 96 + 32 + d] - M4[pn * 96 + 32 + d]); break; // s01
            case 5: v = fabsf(M4[pn * 96 + 32 + d] - Z8[pn * 64 + d]); break;      // s02
            case 6: v = fabsf(M4[pn * 96 + 64 + d] - Z8[pn * 64 + 32 + d]); break; // s12
        }
        s += v;
    }
    __shared__ float red[8][33];
    red[ty][d] = s;
    __syncthreads();
    if (ty == 0) {
        float tot = 0.0f;
#pragma unroll
        for (int t = 0; t < 8; t++) tot += red[t][d];
        out[(size_t)pair * 224 + g * 32 + d] = tot * (1.0f / 1024.0f);
    }
}

extern "C" void kernel_launch(void* const* d_in, const int* in_sizes, int n_in,
                              void* d_out, int out_size, void* d_ws, size_t ws_size,
                              hipStream_t stream) {
    const float* pc     = (const float*)d_in[0];
    const float* alphas = (const float*)d_in[1];
    const float* sigp   = (const float*)d_in[2];
    float* out = (float*)d_out;
    float* ws = (float*)d_ws;

    const size_t SZ32 = (size_t)NPAIR * NPTS * 32;    // 524288
    const size_t SZ64 = (size_t)NPAIR * NPTS * 64;    // 1048576
    const size_t SZ96 = (size_t)NPAIR * NPTS * 96;    // 1572864

    float* X    = ws;                       // SZ32
    float* sqX  = X + SZ32;                 // 16384
    float* deg  = sqX + 16384;              // 16384
    float* P    = deg + 16384;              // 16 M
    float* part = P + (size_t)NPAIR * NPTS * NPTS;  // max 2*SZ96 = 3145728
    float* A1   = part + 2 * SZ96;
    float* A2   = A1 + SZ32;
    float* A3   = A2 + SZ32;
    float* M0   = A3 + SZ32;                // SZ96
    float* M2   = M0 + SZ96;
    float* M4   = M2 + SZ96;
    float* Mtmp = M4 + SZ96;
    float* N2b  = Mtmp + SZ96;              // SZ64
    float* Z8   = N2b + SZ64;               // SZ64; end = 30,441,472 floats = 121.8 MB

    dim3 b256(256);

    build_X<<<dim3(SZ32 / 256), b256, 0, stream>>>(pc, alphas, X, sqX);
    deg_kernel<<<dim3(16, NPAIR), b256, 0, stream>>>(X, sqX, sigp, deg);
    P_kernel<<<dim3(16, NPAIR), b256, 0, stream>>>(X, sqX, sigp, deg, P);

    // ---- A-chain (D=32, ksplit=4): A1=PX, A2, A3, A4 -> M0[:,0:32] ----
    auto apply32 = [&](const float* Y, int ystr, int yoff, float* dst, int dstr, int doff) {
        apply_partial<32, 4><<<dim3(16, 4, NPAIR), dim3(128), 0, stream>>>(P, Y, part, ystr, yoff);
        reduce_partial<32, 4><<<dim3(SZ32 / 1024), b256, 0, stream>>>(part, dst, dstr, doff);
    };
    apply32(X, 32, 0, A1, 32, 0);
    apply32(A1, 32, 0, A2, 32, 0);
    apply32(A2, 32, 0, A3, 32, 0);
    apply32(A3, 32, 0, M0, 96, 0);   // A4 = T4 into M0 cols 0..31

    build_M0<<<dim3(SZ32 / 256), b256, 0, stream>>>(A1, A2, M0);

    // ---- M-chain (D=96, ksplit=2): M4 = P^4 M0 ; keep M2 ----
    auto apply96 = [&](const float* Y, float* dst) {
        apply_partial<96, 2><<<dim3(16, 2, NPAIR), dim3(384), 0, stream>>>(P, Y, part, 96, 0);
        reduce_partial<96, 2><<<dim3(SZ96 / 1024), b256, 0, stream>>>(part, dst, 96, 0);
    };
    apply96(M0, Mtmp);    // M1
    apply96(Mtmp, M2);    // M2
    apply96(M2, Mtmp);    // M3
    apply96(Mtmp, M4);    // M4 = [T8 | Z4]

    // ---- N-chain (D=64, ksplit=2): Z8 = P^4 Z4, Z4 = M4[:,32:96] ----
    auto apply64 = [&](const float* Y, int ystr, int yoff, float* dst) {
        apply_partial<64, 2><<<dim3(16, 2, NPAIR), dim3(256), 0, stream>>>(P, Y, part, ystr, yoff);
        reduce_partial<64, 2><<<dim3(SZ64 / 1024), b256, 0, stream>>>(part, dst, 64, 0);
    };
    apply64(M4, 96, 32, Mtmp);   // N1
    apply64(Mtmp, 64, 0, N2b);   // N2
    apply64(N2b, 64, 0, Mtmp);   // N3
    apply64(Mtmp, 64, 0, Z8);    // N4 = Z8

    pool_kernel<<<dim3(7, NPAIR), dim3(32, 8), 0, stream>>>(X, M0, M2, M4, Z8, out);
}

// Round 3
// 550.652 us; speedup vs baseline: 2.7674x; 1.4324x over previous
//
#include <hip/hip_runtime.h>
#include <math.h>

#define NPTS 1024
#define DIM 32
#define NPAIR 16   // B*NW

typedef __attribute__((ext_vector_type(8))) short short8;
typedef __attribute__((ext_vector_type(4))) float f32x4;
typedef __attribute__((ext_vector_type(8))) unsigned short ushort8v;
typedef __attribute__((ext_vector_type(4))) unsigned short ushort4v;

// RNE float -> bf16 bits
__device__ __forceinline__ unsigned short bf16_rne(float v) {
    unsigned u = __float_as_uint(v);
    return (unsigned short)((u + 0x7fffu + ((u >> 16) & 1u)) >> 16);
}
__device__ __forceinline__ float bf16_to_f32(unsigned short b) {
    return __uint_as_float(((unsigned)b) << 16);
}

// ============ build X + sqX + XT hi/lo (bf16 transposed) ============
// grid (16 ntiles, NPAIR), block 256
__global__ __launch_bounds__(256) void build_X(const float* __restrict__ pc,
                                               const float* __restrict__ alphas,
                                               float* __restrict__ X,
                                               float* __restrict__ sqX,
                                               unsigned short* __restrict__ hiT,
                                               unsigned short* __restrict__ loT) {
    __shared__ float S[DIM][68];
    int pair = blockIdx.y, n0 = blockIdx.x * 64, tid = threadIdx.x;
    int b = pair >> 2, w = pair & 3;
    for (int e = tid; e < 512; e += 256) {
        int e4 = e * 4;
        int dn = e4 >> 5, dq = e4 & 31;
        float4 p = *(const float4*)&pc[((size_t)b * NPTS + n0 + dn) * DIM + dq];
        float4 al = *(const float4*)&alphas[w * DIM + dq];
        float4 x = make_float4(p.x * al.x, p.y * al.y, p.z * al.z, p.w * al.w);
        *(float4*)&X[((size_t)pair * NPTS + n0 + dn) * DIM + dq] = x;
        S[dq][dn] = x.x; S[dq + 1][dn] = x.y; S[dq + 2][dn] = x.z; S[dq + 3][dn] = x.w;
    }
    __syncthreads();
    if (tid < 64) {
        float s = 0.f;
#pragma unroll
        for (int d = 0; d < DIM; d++) { float v = S[d][tid]; s += v * v; }
        sqX[pair * NPTS + n0 + tid] = s;
    }
    for (int idx = tid; idx < DIM * 4; idx += 256) {
        int row = idx >> 2, nq = (idx & 3) * 16;
        ushort8v hv[2], lv[2];
#pragma unroll
        for (int i = 0; i < 16; i++) {
            float v = S[row][nq + i];
            unsigned short hb = bf16_rne(v);
            float lo = v - bf16_to_f32(hb);
            hv[i >> 3][i & 7] = hb;
            lv[i >> 3][i & 7] = bf16_rne(lo);
        }
        size_t o = ((size_t)pair * DIM + row) * NPTS + n0 + nq;
        *(ushort8v*)(hiT + o) = hv[0]; *(ushort8v*)(hiT + o + 8) = hv[1];
        *(ushort8v*)(loT + o) = lv[0]; *(ushort8v*)(loT + o + 8) = lv[1];
    }
}

// ============ deg: deg[i] = sum_j W_ij (atomic partials over 4 j-slices) ============
// grid (16 rowtiles, 4 jslices, NPAIR), block 256
__global__ __launch_bounds__(256) void deg_kernel(const float* __restrict__ X,
                                                  const float* __restrict__ sqX,
                                                  const float* __restrict__ sigp,
                                                  float* __restrict__ deg) {
    int pair = blockIdx.z;
    int i0 = blockIdx.x * 64, j0 = blockIdx.y * 256;
    float rsig = -1.0f / (*sigp);
    const float* Xp = X + (size_t)pair * NPTS * DIM;

    __shared__ float XiT[DIM][68];
    __shared__ float XjT[DIM][68];
    __shared__ float sqjS[64];

    int tid = threadIdx.x;
    int cx = tid & 15, ry = tid >> 4;

    {   // conflict-free transpose staging: lane covers all 64 rows, fixed d-group
        int r = tid & 63, dgb = (tid >> 6) * 4;
#pragma unroll
        for (int p = 0; p < 2; p++) {
            int dg = dgb + p * 16;
            float4 v = *(const float4*)&Xp[(size_t)(i0 + r) * DIM + dg];
            XiT[dg][r] = v.x; XiT[dg + 1][r] = v.y; XiT[dg + 2][r] = v.z; XiT[dg + 3][r] = v.w;
        }
    }
    float sqi[4];
#pragma unroll
    for (int a = 0; a < 4; a++) sqi[a] = sqX[pair * NPTS + i0 + ry * 4 + a];

    float rs[4] = {0.f, 0.f, 0.f, 0.f};
    for (int jt = 0; jt < 256; jt += 64) {
        __syncthreads();
        {
            int r = tid & 63, dgb = (tid >> 6) * 4;
#pragma unroll
            for (int p = 0; p < 2; p++) {
                int dg = dgb + p * 16;
                float4 v = *(const float4*)&Xp[(size_t)(j0 + jt + r) * DIM + dg];
                XjT[dg][r] = v.x; XjT[dg + 1][r] = v.y; XjT[dg + 2][r] = v.z; XjT[dg + 3][r] = v.w;
            }
        }
        if (tid < 64) sqjS[tid] = sqX[pair * NPTS + j0 + jt + tid];
        __syncthreads();

        float dot[4][4] = {};
#pragma unroll
        for (int d = 0; d < DIM; d++) {
            float4 a = *(const float4*)&XiT[d][ry * 4];
            float4 b = *(const float4*)&XjT[d][cx * 4];
            dot[0][0] += a.x * b.x; dot[0][1] += a.x * b.y; dot[0][2] += a.x * b.z; dot[0][3] += a.x * b.w;
            dot[1][0] += a.y * b.x; dot[1][1] += a.y * b.y; dot[1][2] += a.y * b.z; dot[1][3] += a.y * b.w;
            dot[2][0] += a.z * b.x; dot[2][1] += a.z * b.y; dot[2][2] += a.z * b.z; dot[2][3] += a.z * b.w;
            dot[3][0] += a.w * b.x; dot[3][1] += a.w * b.y; dot[3][2] += a.w * b.z; dot[3][3] += a.w * b.w;
        }
#pragma unroll
        for (int a = 0; a < 4; a++) {
#pragma unroll
            for (int bb = 0; bb < 4; bb++) {
                float Dm = sqi[a] + sqjS[cx * 4 + bb] - 2.0f * dot[a][bb];
                float K = __expf(Dm * rsig);
                rs[a] += (K >= 0.5f) ? K : 0.0f;
            }
        }
    }
    // reduce over cx (16-lane groups) then atomic
#pragma unroll
    for (int a = 0; a < 4; a++) {
        float s = rs[a];
        s += __shfl_xor(s, 1); s += __shfl_xor(s, 2);
        s += __shfl_xor(s, 4); s += __shfl_xor(s, 8);
        if (cx == 0) atomicAdd(&deg[pair * NPTS + i0 + ry * 4 + a], s);
    }
}

// ============ P = 0.5*(I + W/deg) -> Phi/Plo bf16 ============
// grid (16 rowtiles, 4 jslices, NPAIR), block 256
__global__ __launch_bounds__(256) void P_kernel(const float* __restrict__ X,
                                                const float* __restrict__ sqX,
                                                const float* __restrict__ sigp,
                                                const float* __restrict__ deg,
                                                unsigned short* __restrict__ Phi,
                                                unsigned short* __restrict__ Plo) {
    int pair = blockIdx.z;
    int i0 = blockIdx.x * 64, j0 = blockIdx.y * 256;
    float rsig = -1.0f / (*sigp);
    const float* Xp = X + (size_t)pair * NPTS * DIM;

    __shared__ float XiT[DIM][68];
    __shared__ float XjT[DIM][68];
    __shared__ float sqjS[64];

    int tid = threadIdx.x;
    int cx = tid & 15, ry = tid >> 4;

    {
        int r = tid & 63, dgb = (tid >> 6) * 4;
#pragma unroll
        for (int p = 0; p < 2; p++) {
            int dg = dgb + p * 16;
            float4 v = *(const float4*)&Xp[(size_t)(i0 + r) * DIM + dg];
            XiT[dg][r] = v.x; XiT[dg + 1][r] = v.y; XiT[dg + 2][r] = v.z; XiT[dg + 3][r] = v.w;
        }
    }
    float sqi[4], rdeg[4];
#pragma unroll
    for (int a = 0; a < 4; a++) {
        sqi[a] = sqX[pair * NPTS + i0 + ry * 4 + a];
        rdeg[a] = 0.5f / deg[pair * NPTS + i0 + ry * 4 + a];
    }

    for (int jt = 0; jt < 256; jt += 64) {
        __syncthreads();
        {
            int r = tid & 63, dgb = (tid >> 6) * 4;
#pragma unroll
            for (int p = 0; p < 2; p++) {
                int dg = dgb + p * 16;
                float4 v = *(const float4*)&Xp[(size_t)(j0 + jt + r) * DIM + dg];
                XjT[dg][r] = v.x; XjT[dg + 1][r] = v.y; XjT[dg + 2][r] = v.z; XjT[dg + 3][r] = v.w;
            }
        }
        if (tid < 64) sqjS[tid] = sqX[pair * NPTS + j0 + jt + tid];
        __syncthreads();

        float dot[4][4] = {};
#pragma unroll
        for (int d = 0; d < DIM; d++) {
            float4 a = *(const float4*)&XiT[d][ry * 4];
            float4 b = *(const float4*)&XjT[d][cx * 4];
            dot[0][0] += a.x * b.x; dot[0][1] += a.x * b.y; dot[0][2] += a.x * b.z; dot[0][3] += a.x * b.w;
            dot[1][0] += a.y * b.x; dot[1][1] += a.y * b.y; dot[1][2] += a.y * b.z; dot[1][3] += a.y * b.w;
            dot[2][0] += a.z * b.x; dot[2][1] += a.z * b.y; dot[2][2] += a.z * b.z; dot[2][3] += a.z * b.w;
            dot[3][0] += a.w * b.x; dot[3][1] += a.w * b.y; dot[3][2] += a.w * b.z; dot[3][3] += a.w * b.w;
        }
#pragma unroll
        for (int a = 0; a < 4; a++) {
            int i = i0 + ry * 4 + a;
            int jb = j0 + jt + cx * 4;
            ushort4v hv, lv;
#pragma unroll
            for (int bb = 0; bb < 4; bb++) {
                float Dm = sqi[a] + sqjS[cx * 4 + bb] - 2.0f * dot[a][bb];
                float K = __expf(Dm * rsig);
                float W = (K >= 0.5f) ? K : 0.0f;
                float Pv = W * rdeg[a] + ((i == jb + bb) ? 0.5f : 0.0f);
                unsigned short hb = bf16_rne(Pv);
                hv[bb] = hb;
                lv[bb] = bf16_rne(Pv - bf16_to_f32(hb));
            }
            size_t o = ((size_t)pair * NPTS + i) * NPTS + jb;
            *(ushort4v*)(Phi + o) = hv;
            *(ushort4v*)(Plo + o) = lv;
        }
    }
}

// ============ MFMA apply: part[slice] = P[:, slice] @ Y[slice, :] (bf16x3 split) ============
// grid (32 rowtiles, 2 kslices, NPAIR), block 64 (one wave, 2 m-tiles, all n-tiles)
template <int DC>
__global__ __launch_bounds__(64) void apply_mfma(const unsigned short* __restrict__ Phi,
                                                 const unsigned short* __restrict__ Plo,
                                                 const unsigned short* __restrict__ Yhi,
                                                 const unsigned short* __restrict__ Ylo,
                                                 float* __restrict__ part) {
    constexpr int NT = DC / 16;
    int pair = blockIdx.z, slice = blockIdx.y;
    int r0 = blockIdx.x * 32;
    int lane = threadIdx.x;
    int m = lane & 15, quad = lane >> 4;
    int kb = slice * 512;

    size_t aoff = (size_t)(pair * NPTS + r0 + m) * NPTS + kb + quad * 8;
    size_t boff = ((size_t)pair * DC + m) * NPTS + kb + quad * 8;

    f32x4 acc[2][NT];
#pragma unroll
    for (int mt = 0; mt < 2; mt++)
#pragma unroll
        for (int nt = 0; nt < NT; nt++)
#pragma unroll
            for (int i = 0; i < 4; i++) acc[mt][nt][i] = 0.0f;

#pragma unroll 2
    for (int c = 0; c < 16; c++) {
        int ko = c * 32;
        short8 a0h = *(const short8*)(Phi + aoff + ko);
        short8 a0l = *(const short8*)(Plo + aoff + ko);
        short8 a1h = *(const short8*)(Phi + aoff + 16 * NPTS + ko);
        short8 a1l = *(const short8*)(Plo + aoff + 16 * NPTS + ko);
#pragma unroll
        for (int nt = 0; nt < NT; nt++) {
            short8 bh = *(const short8*)(Yhi + boff + (size_t)nt * 16 * NPTS + ko);
            short8 bl = *(const short8*)(Ylo + boff + (size_t)nt * 16 * NPTS + ko);
            acc[0][nt] = __builtin_amdgcn_mfma_f32_16x16x32_bf16(a0h, bh, acc[0][nt], 0, 0, 0);
            acc[0][nt] = __builtin_amdgcn_mfma_f32_16x16x32_bf16(a0l, bh, acc[0][nt], 0, 0, 0);
            acc[0][nt] = __builtin_amdgcn_mfma_f32_16x16x32_bf16(a0h, bl, acc[0][nt], 0, 0, 0);
            acc[1][nt] = __builtin_amdgcn_mfma_f32_16x16x32_bf16(a1h, bh, acc[1][nt], 0, 0, 0);
            acc[1][nt] = __builtin_amdgcn_mfma_f32_16x16x32_bf16(a1l, bh, acc[1][nt], 0, 0, 0);
            acc[1][nt] = __builtin_amdgcn_mfma_f32_16x16x32_bf16(a1h, bl, acc[1][nt], 0, 0, 0);
        }
    }

    float* po = part + ((size_t)(slice * NPAIR + pair) * NPTS) * DC;
#pragma unroll
    for (int mt = 0; mt < 2; mt++)
#pragma unroll
        for (int nt = 0; nt < NT; nt++)
#pragma unroll
            for (int i = 0; i < 4; i++) {
                int row = r0 + mt * 16 + quad * 4 + i;
                int col = nt * 16 + m;
                po[(size_t)row * DC + col] = acc[mt][nt][i];
            }
}

// ============ reduce 2 partials -> optional fp32 dst + optional bf16 hi/lo transposed ============
// grid (16 ntiles, NPAIR), block 256
template <int DC>
__global__ __launch_bounds__(256) void reduce_split(const float* __restrict__ part,
                                                    float* __restrict__ dstF, int dstStride,
                                                    int dstOff, int dstC0, int dstC1,
                                                    unsigned short* __restrict__ hiT,
                                                    unsigned short* __restrict__ loT,
                                                    int tC0, int tCN) {
    constexpr int ELEMS4 = 64 * DC / 4;
    __shared__ float S[DC][68];
    int pair = blockIdx.y, n0 = blockIdx.x * 64, tid = threadIdx.x;
    const float* p0 = part + ((size_t)pair * NPTS + n0) * DC;
    const float* p1 = part + ((size_t)(NPAIR + pair) * NPTS + n0) * DC;
    for (int e = tid; e < ELEMS4; e += 256) {
        int e4 = e * 4;
        int dn = e4 / DC, c = e4 % DC;
        size_t off = (size_t)dn * DC + c;
        float4 a = *(const float4*)(p0 + off);
        float4 b = *(const float4*)(p1 + off);
        float4 s = make_float4(a.x + b.x, a.y + b.y, a.z + b.z, a.w + b.w);
        if (dstF && c >= dstC0 && c < dstC1)
            *(float4*)&dstF[((size_t)pair * NPTS + n0 + dn) * dstStride + dstOff + (c - dstC0)] = s;
        S[c][dn] = s.x; S[c + 1][dn] = s.y; S[c + 2][dn] = s.z; S[c + 3][dn] = s.w;
    }
    __syncthreads();
    if (hiT) {
        for (int idx = tid; idx < tCN * 4; idx += 256) {
            int row = idx >> 2, nq = (idx & 3) * 16;
            ushort8v hv[2], lv[2];
#pragma unroll
            for (int i = 0; i < 16; i++) {
                float v = S[tC0 + row][nq + i];
                unsigned short hb = bf16_rne(v);
                hv[i >> 3][i & 7] = hb;
                lv[i >> 3][i & 7] = bf16_rne(v - bf16_to_f32(hb));
            }
            size_t o = ((size_t)pair * tCN + row) * NPTS + n0 + nq;
            *(ushort8v*)(hiT + o) = hv[0]; *(ushort8v*)(hiT + o + 8) = hv[1];
            *(ushort8v*)(loT + o) = lv[0]; *(ushort8v*)(loT + o + 8) = lv[1];
        }
    }
}

// ============ build M0 cols 32..95 fp32 + full M0T hi/lo ============
// grid (16 ntiles, NPAIR), block 256
__global__ __launch_bounds__(256) void build_M0(const float* __restrict__ A1,
                                                const float* __restrict__ A2,
                                                float* __restrict__ M0,
                                                unsigned short* __restrict__ hiT,
                                                unsigned short* __restrict__ loT) {
    __shared__ float S[96][68];
    int pair = blockIdx.y, n0 = blockIdx.x * 64, tid = threadIdx.x;
    for (int e = tid; e < 512; e += 256) {
        int e4 = e * 4;
        int dn = e4 >> 5, dq = e4 & 31;
        size_t pn = (size_t)pair * NPTS + n0 + dn;
        float4 a1 = *(const float4*)&A1[pn * 32 + dq];
        float4 a2 = *(const float4*)&A2[pn * 32 + dq];
        float4 t4 = *(const float4*)&M0[pn * 96 + dq];
        float4 f0 = make_float4(fabsf(a1.x - a2.x), fabsf(a1.y - a2.y), fabsf(a1.z - a2.z), fabsf(a1.w - a2.w));
        float4 f1 = make_float4(fabsf(a2.x - t4.x), fabsf(a2.y - t4.y), fabsf(a2.z - t4.z), fabsf(a2.w - t4.w));
        *(float4*)&M0[pn * 96 + 32 + dq] = f0;
        *(float4*)&M0[pn * 96 + 64 + dq] = f1;
        S[dq][dn] = t4.x; S[dq + 1][dn] = t4.y; S[dq + 2][dn] = t4.z; S[dq + 3][dn] = t4.w;
        S[32 + dq][dn] = f0.x; S[33 + dq][dn] = f0.y; S[34 + dq][dn] = f0.z; S[35 + dq][dn] = f0.w;
        S[64 + dq][dn] = f1.x; S[65 + dq][dn] = f1.y; S[66 + dq][dn] = f1.z; S[67 + dq][dn] = f1.w;
    }
    __syncthreads();
    for (int idx = tid; idx < 96 * 4; idx += 256) {
        int row = idx >> 2, nq = (idx & 3) * 16;
        ushort8v hv[2], lv[2];
#pragma unroll
        for (int i = 0; i < 16; i++) {
            float v = S[row][nq + i];
            unsigned short hb = bf16_rne(v);
            hv[i >> 3][i & 7] = hb;
            lv[i >> 3][i & 7] = bf16_rne(v - bf16_to_f32(hb));
        }
        size_t o = ((size_t)pair * 96 + row) * NPTS + n0 + nq;
        *(ushort8v*)(hiT + o) = hv[0]; *(ushort8v*)(hiT + o + 8) = hv[1];
        *(ushort8v*)(loT + o) = lv[0]; *(ushort8v*)(loT + o + 8) = lv[1];
    }
}

// ============ pooling ============
// grid (7, NPAIR), block (32, 8)
__global__ __launch_bounds__(256) void pool_kernel(const float* __restrict__ X,
                                                   const float* __restrict__ M0,
                                                   const float* __restrict__ M2p,
                                                   const float* __restrict__ M4,
                                                   const float* __restrict__ Z8,
                                                   float* __restrict__ out) {
    int g = blockIdx.x;
    int pair = blockIdx.y;
    int d = threadIdx.x;
    int ty = threadIdx.y;
    float s = 0.0f;
    for (int n = ty; n < NPTS; n += 8) {
        size_t pn = (size_t)pair * NPTS + n;
        float v = 0.0f;
        switch (g) {
            case 0: v = X[pn * 32 + d]; break;
            case 1: v = M0[pn * 96 + 32 + d]; break;
            case 2: v = M0[pn * 96 + 64 + d]; break;
            case 3: v = fabsf(M0[pn * 96 + d] - M4[pn * 96 + d]); break;
            case 4: v = fabsf(M2p[pn * 32 + d] - M4[pn * 96 + 32 + d]); break;
            case 5: v = fabsf(M4[pn * 96 + 32 + d] - Z8[pn * 64 + d]); break;
            case 6: v = fabsf(M4[pn * 96 + 64 + d] - Z8[pn * 64 + 32 + d]); break;
        }
        s += v;
    }
    __shared__ float red[8][33];
    red[ty][d] = s;
    __syncthreads();
    if (ty == 0) {
        float tot = 0.0f;
#pragma unroll
        for (int t = 0; t < 8; t++) tot += red[t][d];
        out[(size_t)pair * 224 + g * 32 + d] = tot * (1.0f / 1024.0f);
    }
}

extern "C" void kernel_launch(void* const* d_in, const int* in_sizes, int n_in,
                              void* d_out, int out_size, void* d_ws, size_t ws_size,
                              hipStream_t stream) {
    const float* pc     = (const float*)d_in[0];
    const float* alphas = (const float*)d_in[1];
    const float* sigp   = (const float*)d_in[2];
    float* out = (float*)d_out;
    float* ws = (float*)d_ws;

    // ---- workspace layout (float offsets) ----
    float* X    = ws;                         // 524288
    float* sqX  = X + 524288;                 // 16384
    float* deg  = sqX + 16384;                // 16384
    unsigned short* Phi = (unsigned short*)(deg + 16384);        // 16777216 bf16
    unsigned short* Plo = Phi + 16777216;                        // 16777216 bf16
    float* part = (float*)(Plo + 16777216);   // 3145728 floats
    float* A1   = part + 3145728;             // 524288
    float* A2   = A1 + 524288;                // 524288
    unsigned short* T32a_h = (unsigned short*)(A2 + 524288);     // 524288 bf16 each
    unsigned short* T32a_l = T32a_h + 524288;
    unsigned short* T32b_h = T32a_l + 524288;
    unsigned short* T32b_l = T32b_h + 524288;
    float* M0   = (float*)(T32b_l + 524288);  // 1572864
    float* M2p  = M0 + 1572864;               // 524288 (cols 32..63 only)
    float* M4   = M2p + 524288;               // 1572864
    float* Z8   = M4 + 1572864;               // 1048576
    unsigned short* T96a_h = (unsigned short*)(Z8 + 1048576);    // 1572864 bf16 each
    unsigned short* T96a_l = T96a_h + 1572864;
    unsigned short* T96b_h = T96a_l + 1572864;
    unsigned short* T96b_l = T96b_h + 1572864;
    // T64 overlays (regions dead by the time N-chain runs):
    unsigned short* T64a_h = (unsigned short*)A1;     // 1048576 bf16 = A1 region
    unsigned short* T64a_l = (unsigned short*)A2;
    unsigned short* T64b_h = T32a_h;                  // spans T32a_h + T32a_l
    unsigned short* T64b_l = T32b_h;                  // spans T32b_h + T32b_l

    dim3 b256(256);

    build_X<<<dim3(16, NPAIR), b256, 0, stream>>>(pc, alphas, X, sqX, T32a_h, T32a_l);
    hipMemsetAsync(deg, 0, 16384 * sizeof(float), stream);
    deg_kernel<<<dim3(16, 4, NPAIR), b256, 0, stream>>>(X, sqX, sigp, deg);
    P_kernel<<<dim3(16, 4, NPAIR), b256, 0, stream>>>(X, sqX, sigp, deg, Phi, Plo);

    auto ap32 = [&](const unsigned short* yh, const unsigned short* yl) {
        apply_mfma<32><<<dim3(32, 2, NPAIR), dim3(64), 0, stream>>>(Phi, Plo, yh, yl, part);
    };
    auto ap64 = [&](const unsigned short* yh, const unsigned short* yl) {
        apply_mfma<64><<<dim3(32, 2, NPAIR), dim3(64), 0, stream>>>(Phi, Plo, yh, yl, part);
    };
    auto ap96 = [&](const unsigned short* yh, const unsigned short* yl) {
        apply_mfma<96><<<dim3(32, 2, NPAIR), dim3(64), 0, stream>>>(Phi, Plo, yh, yl, part);
    };

    // ---- A-chain (D=32): A1, A2, A3(T only), A4 -> M0 cols 0..31 ----
    ap32(T32a_h, T32a_l);
    reduce_split<32><<<dim3(16, NPAIR), b256, 0, stream>>>(part, A1, 32, 0, 0, 32, T32b_h, T32b_l, 0, 32);
    ap32(T32b_h, T32b_l);
    reduce_split<32><<<dim3(16, NPAIR), b256, 0, stream>>>(part, A2, 32, 0, 0, 32, T32a_h, T32a_l, 0, 32);
    ap32(T32a_h, T32a_l);
    reduce_split<32><<<dim3(16, NPAIR), b256, 0, stream>>>(part, nullptr, 0, 0, 0, 0, T32b_h, T32b_l, 0, 32);
    ap32(T32b_h, T32b_l);
    reduce_split<32><<<dim3(16, NPAIR), b256, 0, stream>>>(part, M0, 96, 0, 0, 32, nullptr, nullptr, 0, 32);

    build_M0<<<dim3(16, NPAIR), b256, 0, stream>>>(A1, A2, M0, T96a_h, T96a_l);

    // ---- M-chain (D=96): M4 = P^4 M0; keep M2 cols 32..63 ----
    ap96(T96a_h, T96a_l);
    reduce_split<96><<<dim3(16, NPAIR), b256, 0, stream>>>(part, nullptr, 0, 0, 0, 0, T96b_h, T96b_l, 0, 96);
    ap96(T96b_h, T96b_l);
    reduce_split<96><<<dim3(16, NPAIR), b256, 0, stream>>>(part, M2p, 32, 0, 32, 64, T96a_h, T96a_l, 0, 96);
    ap96(T96a_h, T96a_l);
    reduce_split<96><<<dim3(16, NPAIR), b256, 0, stream>>>(part, nullptr, 0, 0, 0, 0, T96b_h, T96b_l, 0, 96);
    ap96(T96b_h, T96b_l);
    reduce_split<96><<<dim3(16, NPAIR), b256, 0, stream>>>(part, M4, 96, 0, 0, 96, T64a_h, T64a_l, 32, 64);

    // ---- N-chain (D=64): Z8 = P^4 (M4 cols 32..95) ----
    ap64(T64a_h, T64a_l);
    reduce_split<64><<<dim3(16, NPAIR), b256, 0, stream>>>(part, nullptr, 0, 0, 0, 0, T64b_h, T64b_l, 0, 64);
    ap64(T64b_h, T64b_l);
    reduce_split<64><<<dim3(16, NPAIR), b256, 0, stream>>>(part, nullptr, 0, 0, 0, 0, T64a_h, T64a_l, 0, 64);
    ap64(T64a_h, T64a_l);
    reduce_split<64><<<dim3(16, NPAIR), b256, 0, stream>>>(part, nullptr, 0, 0, 0, 0, T64b_h, T64b_l, 0, 64);
    ap64(T64b_h, T64b_l);
    reduce_split<64><<<dim3(16, NPAIR), b256, 0, stream>>>(part, Z8, 64, 0, 0, 64, nullptr, nullptr, 0, 64);

    pool_kernel<<<dim3(7, NPAIR), dim3(32, 8), 0, stream>>>(X, M0, M2p, M4, Z8, out);
}

// Round 4
// 489.450 us; speedup vs baseline: 3.1134x; 1.1250x over previous
//
#include <hip/hip_runtime.h>
#include <math.h>

#define NPTS 1024
#define DIM 32
#define NPAIR 16   // B*NW

typedef __attribute__((ext_vector_type(8))) short short8;
typedef __attribute__((ext_vector_type(4))) float f32x4;
typedef __attribute__((ext_vector_type(8))) unsigned short ushort8v;
typedef __attribute__((ext_vector_type(4))) unsigned short ushort4v;
typedef unsigned short u16;

// RNE float -> bf16 bits
__device__ __forceinline__ u16 bf16_rne(float v) {
    unsigned u = __float_as_uint(v);
    return (u16)((u + 0x7fffu + ((u >> 16) & 1u)) >> 16);
}
__device__ __forceinline__ float bf16_to_f32(u16 b) {
    return __uint_as_float(((unsigned)b) << 16);
}

// ============ build X + sqX + XT hi/lo (bf16 transposed) ============
// grid (16 ntiles, NPAIR), block 256
__global__ __launch_bounds__(256) void build_X(const float* __restrict__ pc,
                                               const float* __restrict__ alphas,
                                               float* __restrict__ X,
                                               float* __restrict__ sqX,
                                               u16* __restrict__ hiT,
                                               u16* __restrict__ loT) {
    __shared__ float S[DIM][68];
    int pair = blockIdx.y, n0 = blockIdx.x * 64, tid = threadIdx.x;
    int b = pair >> 2, w = pair & 3;
    for (int e = tid; e < 512; e += 256) {
        int e4 = e * 4;
        int dn = e4 >> 5, dq = e4 & 31;
        float4 p = *(const float4*)&pc[((size_t)b * NPTS + n0 + dn) * DIM + dq];
        float4 al = *(const float4*)&alphas[w * DIM + dq];
        float4 x = make_float4(p.x * al.x, p.y * al.y, p.z * al.z, p.w * al.w);
        *(float4*)&X[((size_t)pair * NPTS + n0 + dn) * DIM + dq] = x;
        S[dq][dn] = x.x; S[dq + 1][dn] = x.y; S[dq + 2][dn] = x.z; S[dq + 3][dn] = x.w;
    }
    __syncthreads();
    if (tid < 64) {
        float s = 0.f;
#pragma unroll
        for (int d = 0; d < DIM; d++) { float v = S[d][tid]; s += v * v; }
        sqX[pair * NPTS + n0 + tid] = s;
    }
    for (int idx = tid; idx < DIM * 4; idx += 256) {
        int row = idx >> 2, nq = (idx & 3) * 16;
        ushort8v hv[2], lv[2];
#pragma unroll
        for (int i = 0; i < 16; i++) {
            float v = S[row][nq + i];
            u16 hb = bf16_rne(v);
            hv[i >> 3][i & 7] = hb;
            lv[i >> 3][i & 7] = bf16_rne(v - bf16_to_f32(hb));
        }
        size_t o = ((size_t)pair * DIM + row) * NPTS + n0 + nq;
        *(ushort8v*)(hiT + o) = hv[0]; *(ushort8v*)(hiT + o + 8) = hv[1];
        *(ushort8v*)(loT + o) = lv[0]; *(ushort8v*)(loT + o + 8) = lv[1];
    }
}

// ============ deg: deg[i] = sum_j W_ij (atomic partials over 8 j-slices) ============
// grid (16 rowtiles, 8 jslices, NPAIR), block 256
__global__ __launch_bounds__(256) void deg_kernel(const float* __restrict__ X,
                                                  const float* __restrict__ sqX,
                                                  const float* __restrict__ sigp,
                                                  float* __restrict__ deg) {
    int pair = blockIdx.z;
    int i0 = blockIdx.x * 64, j0 = blockIdx.y * 128;
    float rsig = -1.0f / (*sigp);
    const float* Xp = X + (size_t)pair * NPTS * DIM;

    __shared__ float XiT[DIM][68];
    __shared__ float XjT[DIM][68];
    __shared__ float sqjS[64];

    int tid = threadIdx.x;
    int cx = tid & 15, ry = tid >> 4;

    {   // conflict-free transpose staging
        int r = tid & 63, dgb = (tid >> 6) * 4;
#pragma unroll
        for (int p = 0; p < 2; p++) {
            int dg = dgb + p * 16;
            float4 v = *(const float4*)&Xp[(size_t)(i0 + r) * DIM + dg];
            XiT[dg][r] = v.x; XiT[dg + 1][r] = v.y; XiT[dg + 2][r] = v.z; XiT[dg + 3][r] = v.w;
        }
    }
    float sqi[4];
#pragma unroll
    for (int a = 0; a < 4; a++) sqi[a] = sqX[pair * NPTS + i0 + ry * 4 + a];

    float rs[4] = {0.f, 0.f, 0.f, 0.f};
    for (int jt = 0; jt < 128; jt += 64) {
        __syncthreads();
        {
            int r = tid & 63, dgb = (tid >> 6) * 4;
#pragma unroll
            for (int p = 0; p < 2; p++) {
                int dg = dgb + p * 16;
                float4 v = *(const float4*)&Xp[(size_t)(j0 + jt + r) * DIM + dg];
                XjT[dg][r] = v.x; XjT[dg + 1][r] = v.y; XjT[dg + 2][r] = v.z; XjT[dg + 3][r] = v.w;
            }
        }
        if (tid < 64) sqjS[tid] = sqX[pair * NPTS + j0 + jt + tid];
        __syncthreads();

        float dot[4][4] = {};
#pragma unroll
        for (int d = 0; d < DIM; d++) {
            float4 a = *(const float4*)&XiT[d][ry * 4];
            float4 b = *(const float4*)&XjT[d][cx * 4];
            dot[0][0] += a.x * b.x; dot[0][1] += a.x * b.y; dot[0][2] += a.x * b.z; dot[0][3] += a.x * b.w;
            dot[1][0] += a.y * b.x; dot[1][1] += a.y * b.y; dot[1][2] += a.y * b.z; dot[1][3] += a.y * b.w;
            dot[2][0] += a.z * b.x; dot[2][1] += a.z * b.y; dot[2][2] += a.z * b.z; dot[2][3] += a.z * b.w;
            dot[3][0] += a.w * b.x; dot[3][1] += a.w * b.y; dot[3][2] += a.w * b.z; dot[3][3] += a.w * b.w;
        }
#pragma unroll
        for (int a = 0; a < 4; a++) {
#pragma unroll
            for (int bb = 0; bb < 4; bb++) {
                float Dm = sqi[a] + sqjS[cx * 4 + bb] - 2.0f * dot[a][bb];
                float K = __expf(Dm * rsig);
                rs[a] += (K >= 0.5f) ? K : 0.0f;
            }
        }
    }
#pragma unroll
    for (int a = 0; a < 4; a++) {
        float s = rs[a];
        s += __shfl_xor(s, 1); s += __shfl_xor(s, 2);
        s += __shfl_xor(s, 4); s += __shfl_xor(s, 8);
        if (cx == 0) atomicAdd(&deg[pair * NPTS + i0 + ry * 4 + a], s);
    }
}

// ============ P = 0.5*(I + W/deg) -> Phi/Plo bf16 ============
// grid (16 rowtiles, 4 jslices, NPAIR), block 256
__global__ __launch_bounds__(256) void P_kernel(const float* __restrict__ X,
                                                const float* __restrict__ sqX,
                                                const float* __restrict__ sigp,
                                                const float* __restrict__ deg,
                                                u16* __restrict__ Phi,
                                                u16* __restrict__ Plo) {
    int pair = blockIdx.z;
    int i0 = blockIdx.x * 64, j0 = blockIdx.y * 256;
    float rsig = -1.0f / (*sigp);
    const float* Xp = X + (size_t)pair * NPTS * DIM;

    __shared__ float XiT[DIM][68];
    __shared__ float XjT[DIM][68];
    __shared__ float sqjS[64];

    int tid = threadIdx.x;
    int cx = tid & 15, ry = tid >> 4;

    {
        int r = tid & 63, dgb = (tid >> 6) * 4;
#pragma unroll
        for (int p = 0; p < 2; p++) {
            int dg = dgb + p * 16;
            float4 v = *(const float4*)&Xp[(size_t)(i0 + r) * DIM + dg];
            XiT[dg][r] = v.x; XiT[dg + 1][r] = v.y; XiT[dg + 2][r] = v.z; XiT[dg + 3][r] = v.w;
        }
    }
    float sqi[4], rdeg[4];
#pragma unroll
    for (int a = 0; a < 4; a++) {
        sqi[a] = sqX[pair * NPTS + i0 + ry * 4 + a];
        rdeg[a] = 0.5f / deg[pair * NPTS + i0 + ry * 4 + a];
    }

    for (int jt = 0; jt < 256; jt += 64) {
        __syncthreads();
        {
            int r = tid & 63, dgb = (tid >> 6) * 4;
#pragma unroll
            for (int p = 0; p < 2; p++) {
                int dg = dgb + p * 16;
                float4 v = *(const float4*)&Xp[(size_t)(j0 + jt + r) * DIM + dg];
                XjT[dg][r] = v.x; XjT[dg + 1][r] = v.y; XjT[dg + 2][r] = v.z; XjT[dg + 3][r] = v.w;
            }
        }
        if (tid < 64) sqjS[tid] = sqX[pair * NPTS + j0 + jt + tid];
        __syncthreads();

        float dot[4][4] = {};
#pragma unroll
        for (int d = 0; d < DIM; d++) {
            float4 a = *(const float4*)&XiT[d][ry * 4];
            float4 b = *(const float4*)&XjT[d][cx * 4];
            dot[0][0] += a.x * b.x; dot[0][1] += a.x * b.y; dot[0][2] += a.x * b.z; dot[0][3] += a.x * b.w;
            dot[1][0] += a.y * b.x; dot[1][1] += a.y * b.y; dot[1][2] += a.y * b.z; dot[1][3] += a.y * b.w;
            dot[2][0] += a.z * b.x; dot[2][1] += a.z * b.y; dot[2][2] += a.z * b.z; dot[2][3] += a.z * b.w;
            dot[3][0] += a.w * b.x; dot[3][1] += a.w * b.y; dot[3][2] += a.w * b.z; dot[3][3] += a.w * b.w;
        }
#pragma unroll
        for (int a = 0; a < 4; a++) {
            int i = i0 + ry * 4 + a;
            int jb = j0 + jt + cx * 4;
            ushort4v hv, lv;
#pragma unroll
            for (int bb = 0; bb < 4; bb++) {
                float Dm = sqi[a] + sqjS[cx * 4 + bb] - 2.0f * dot[a][bb];
                float K = __expf(Dm * rsig);
                float W = (K >= 0.5f) ? K : 0.0f;
                float Pv = W * rdeg[a] + ((i == jb + bb) ? 0.5f : 0.0f);
                u16 hb = bf16_rne(Pv);
                hv[bb] = hb;
                lv[bb] = bf16_rne(Pv - bf16_to_f32(hb));
            }
            size_t o = ((size_t)pair * NPTS + i) * NPTS + jb;
            *(ushort4v*)(Phi + o) = hv;
            *(ushort4v*)(Plo + o) = lv;
        }
    }
}

// ============ fused apply: O = P @ Y (bf16x3), in-block k-split=4, fused reduce+outputs ============
// grid (32 rowtiles, NPAIR), block 256 (4 waves; wave w owns k-quarter w)
// Outputs: optional fp32 dstF (cols [dstC0,dstC1) -> dstF[.. dstStride + dstOff ..])
//          optional bf16 hi/lo transposed operand from cols [tC0, tC0+tCN)
template <int DC>
__global__ __launch_bounds__(256) void apply_fused(const u16* __restrict__ Phi,
                                                   const u16* __restrict__ Plo,
                                                   const u16* __restrict__ Yhi,
                                                   const u16* __restrict__ Ylo,
                                                   float* __restrict__ dstF, int dstStride,
                                                   int dstOff, int dstC0, int dstC1,
                                                   u16* __restrict__ hiT, u16* __restrict__ loT,
                                                   int tC0, int tCN) {
    constexpr int NT = DC / 16;
    constexpr int SP = DC + 8;          // row pitch: keeps float4 16B-aligned, bank shift 8
    __shared__ float S[4][32][SP];
    int pair = blockIdx.y;
    int r0 = blockIdx.x * 32;
    int tid = threadIdx.x;
    int wv = tid >> 6, lane = tid & 63;
    int m = lane & 15, quad = lane >> 4;
    int kb = wv * 256;

    size_t aoff = ((size_t)pair * NPTS + r0 + m) * NPTS + kb + quad * 8;
    size_t boff = ((size_t)pair * DC + m) * NPTS + kb + quad * 8;

    f32x4 acc[2][NT];
#pragma unroll
    for (int mt = 0; mt < 2; mt++)
#pragma unroll
        for (int nt = 0; nt < NT; nt++)
#pragma unroll
            for (int i = 0; i < 4; i++) acc[mt][nt][i] = 0.0f;

#pragma unroll 2
    for (int c = 0; c < 8; c++) {
        int ko = c * 32;
        short8 a0h = *(const short8*)(Phi + aoff + ko);
        short8 a0l = *(const short8*)(Plo + aoff + ko);
        short8 a1h = *(const short8*)(Phi + aoff + 16 * NPTS + ko);
        short8 a1l = *(const short8*)(Plo + aoff + 16 * NPTS + ko);
#pragma unroll
        for (int nt = 0; nt < NT; nt++) {
            short8 bh = *(const short8*)(Yhi + boff + (size_t)nt * 16 * NPTS + ko);
            short8 bl = *(const short8*)(Ylo + boff + (size_t)nt * 16 * NPTS + ko);
            acc[0][nt] = __builtin_amdgcn_mfma_f32_16x16x32_bf16(a0h, bh, acc[0][nt], 0, 0, 0);
            acc[0][nt] = __builtin_amdgcn_mfma_f32_16x16x32_bf16(a0l, bh, acc[0][nt], 0, 0, 0);
            acc[0][nt] = __builtin_amdgcn_mfma_f32_16x16x32_bf16(a0h, bl, acc[0][nt], 0, 0, 0);
            acc[1][nt] = __builtin_amdgcn_mfma_f32_16x16x32_bf16(a1h, bh, acc[1][nt], 0, 0, 0);
            acc[1][nt] = __builtin_amdgcn_mfma_f32_16x16x32_bf16(a1l, bh, acc[1][nt], 0, 0, 0);
            acc[1][nt] = __builtin_amdgcn_mfma_f32_16x16x32_bf16(a1h, bl, acc[1][nt], 0, 0, 0);
        }
    }

    // phase 1: each wave deposits its partial tile (C layout: row=quad*4+i, col=m)
#pragma unroll
    for (int mt = 0; mt < 2; mt++)
#pragma unroll
        for (int nt = 0; nt < NT; nt++)
#pragma unroll
            for (int i = 0; i < 4; i++)
                S[wv][mt * 16 + quad * 4 + i][nt * 16 + m] = acc[mt][nt][i];
    __syncthreads();

    // phase 2: sum 4 k-quarters, write optional fp32, stash result in S[0]
    constexpr int E2 = 32 * DC / 4;
    for (int e = tid; e < E2; e += 256) {
        int e4 = e * 4;
        int n = e4 / DC, d = e4 % DC;
        float4 s0 = *(const float4*)&S[0][n][d];
        float4 s1 = *(const float4*)&S[1][n][d];
        float4 s2 = *(const float4*)&S[2][n][d];
        float4 s3 = *(const float4*)&S[3][n][d];
        float4 s = make_float4(s0.x + s1.x + s2.x + s3.x, s0.y + s1.y + s2.y + s3.y,
                               s0.z + s1.z + s2.z + s3.z, s0.w + s1.w + s2.w + s3.w);
        if (dstF && d >= dstC0 && d < dstC1)
            *(float4*)&dstF[((size_t)pair * NPTS + r0 + n) * dstStride + dstOff + (d - dstC0)] = s;
        *(float4*)&S[0][n][d] = s;
    }
    __syncthreads();

    // phase 3: transposed bf16 hi/lo operand for the next step
    if (hiT) {
        for (int e = tid; e < tCN * 4; e += 256) {
            int row = e >> 2, nq = (e & 3) * 8;
            ushort8v hv, lv;
#pragma unroll
            for (int j = 0; j < 8; j++) {
                float v = S[0][nq + j][tC0 + row];
                u16 hb = bf16_rne(v);
                hv[j] = hb;
                lv[j] = bf16_rne(v - bf16_to_f32(hb));
            }
            size_t o = ((size_t)pair * tCN + row) * NPTS + r0 + nq;
            *(ushort8v*)(hiT + o) = hv;
            *(ushort8v*)(loT + o) = lv;
        }
    }
}

// ============ build M0 cols 32..95 fp32 + full M0T hi/lo ============
// grid (16 ntiles, NPAIR), block 256
__global__ __launch_bounds__(256) void build_M0(const float* __restrict__ A1,
                                                const float* __restrict__ A2,
                                                float* __restrict__ M0,
                                                u16* __restrict__ hiT,
                                                u16* __restrict__ loT) {
    __shared__ float S[96][68];
    int pair = blockIdx.y, n0 = blockIdx.x * 64, tid = threadIdx.x;
    for (int e = tid; e < 512; e += 256) {
        int e4 = e * 4;
        int dn = e4 >> 5, dq = e4 & 31;
        size_t pn = (size_t)pair * NPTS + n0 + dn;
        float4 a1 = *(const float4*)&A1[pn * 32 + dq];
        float4 a2 = *(const float4*)&A2[pn * 32 + dq];
        float4 t4 = *(const float4*)&M0[pn * 96 + dq];
        float4 f0 = make_float4(fabsf(a1.x - a2.x), fabsf(a1.y - a2.y), fabsf(a1.z - a2.z), fabsf(a1.w - a2.w));
        float4 f1 = make_float4(fabsf(a2.x - t4.x), fabsf(a2.y - t4.y), fabsf(a2.z - t4.z), fabsf(a2.w - t4.w));
        *(float4*)&M0[pn * 96 + 32 + dq] = f0;
        *(float4*)&M0[pn * 96 + 64 + dq] = f1;
        S[dq][dn] = t4.x; S[dq + 1][dn] = t4.y; S[dq + 2][dn] = t4.z; S[dq + 3][dn] = t4.w;
        S[32 + dq][dn] = f0.x; S[33 + dq][dn] = f0.y; S[34 + dq][dn] = f0.z; S[35 + dq][dn] = f0.w;
        S[64 + dq][dn] = f1.x; S[65 + dq][dn] = f1.y; S[66 + dq][dn] = f1.z; S[67 + dq][dn] = f1.w;
    }
    __syncthreads();
    for (int idx = tid; idx < 96 * 4; idx += 256) {
        int row = idx >> 2, nq = (idx & 3) * 16;
        ushort8v hv[2], lv[2];
#pragma unroll
        for (int i = 0; i < 16; i++) {
            float v = S[row][nq + i];
            u16 hb = bf16_rne(v);
            hv[i >> 3][i & 7] = hb;
            lv[i >> 3][i & 7] = bf16_rne(v - bf16_to_f32(hb));
        }
        size_t o = ((size_t)pair * 96 + row) * NPTS + n0 + nq;
        *(ushort8v*)(hiT + o) = hv[0]; *(ushort8v*)(hiT + o + 8) = hv[1];
        *(ushort8v*)(loT + o) = lv[0]; *(ushort8v*)(loT + o + 8) = lv[1];
    }
}

// ============ pooling: grid (7, NPAIR, 8 nslices), block (32,8), atomic accumulate ============
__global__ __launch_bounds__(256) void pool_kernel(const float* __restrict__ X,
                                                   const float* __restrict__ M0,
                                                   const float* __restrict__ M2p,
                                                   const float* __restrict__ M4,
                                                   const float* __restrict__ Z8,
                                                   float* __restrict__ out) {
    int g = blockIdx.x;
    int pair = blockIdx.y;
    int sl = blockIdx.z;
    int d = threadIdx.x;
    int ty = threadIdx.y;
    float s = 0.0f;
    int nend = sl * 128 + 128;
    for (int n = sl * 128 + ty; n < nend; n += 8) {
        size_t pn = (size_t)pair * NPTS + n;
        float v = 0.0f;
        switch (g) {
            case 0: v = X[pn * 32 + d]; break;
            case 1: v = M0[pn * 96 + 32 + d]; break;
            case 2: v = M0[pn * 96 + 64 + d]; break;
            case 3: v = fabsf(M0[pn * 96 + d] - M4[pn * 96 + d]); break;
            case 4: v = fabsf(M2p[pn * 32 + d] - M4[pn * 96 + 32 + d]); break;
            case 5: v = fabsf(M4[pn * 96 + 32 + d] - Z8[pn * 64 + d]); break;
            case 6: v = fabsf(M4[pn * 96 + 64 + d] - Z8[pn * 64 + 32 + d]); break;
        }
        s += v;
    }
    __shared__ float red[8][33];
    red[ty][d] = s;
    __syncthreads();
    if (ty == 0) {
        float tot = 0.0f;
#pragma unroll
        for (int t = 0; t < 8; t++) tot += red[t][d];
        atomicAdd(&out[(size_t)pair * 224 + g * 32 + d], tot * (1.0f / 1024.0f));
    }
}

extern "C" void kernel_launch(void* const* d_in, const int* in_sizes, int n_in,
                              void* d_out, int out_size, void* d_ws, size_t ws_size,
                              hipStream_t stream) {
    const float* pc     = (const float*)d_in[0];
    const float* alphas = (const float*)d_in[1];
    const float* sigp   = (const float*)d_in[2];
    float* out = (float*)d_out;
    float* ws = (float*)d_ws;

    // ---- workspace layout ----
    float* X    = ws;                         // 524288
    float* sqX  = X + 524288;                 // 16384
    float* deg  = sqX + 16384;                // 16384
    u16* Phi = (u16*)(deg + 16384);           // 16777216 bf16
    u16* Plo = Phi + 16777216;                // 16777216 bf16
    float* A1   = (float*)(Plo + 16777216);   // 524288
    float* A2   = A1 + 524288;                // 524288
    u16* T32a_h = (u16*)(A2 + 524288);        // 524288 bf16 each
    u16* T32a_l = T32a_h + 524288;
    u16* T32b_h = T32a_l + 524288;
    u16* T32b_l = T32b_h + 524288;
    float* M0   = (float*)(T32b_l + 524288);  // 1572864
    float* M2p  = M0 + 1572864;               // 524288 (cols 32..63 only)
    float* M4   = M2p + 524288;               // 1572864
    float* Z8   = M4 + 1572864;               // 1048576
    u16* T96a_h = (u16*)(Z8 + 1048576);       // 1572864 bf16 each
    u16* T96a_l = T96a_h + 1572864;
    u16* T96b_h = T96a_l + 1572864;
    u16* T96b_l = T96b_h + 1572864;
    // T64 overlays (regions dead by the time the N-chain runs):
    u16* T64a_h = (u16*)A1;
    u16* T64a_l = (u16*)A2;
    u16* T64b_h = T32a_h;
    u16* T64b_l = T32b_h;

    dim3 b256(256);
    dim3 gA(32, NPAIR);

    build_X<<<dim3(16, NPAIR), b256, 0, stream>>>(pc, alphas, X, sqX, T32a_h, T32a_l);
    hipMemsetAsync(deg, 0, 16384 * sizeof(float), stream);
    deg_kernel<<<dim3(16, 8, NPAIR), b256, 0, stream>>>(X, sqX, sigp, deg);
    P_kernel<<<dim3(16, 4, NPAIR), b256, 0, stream>>>(X, sqX, sigp, deg, Phi, Plo);

    // ---- A-chain (D=32) ----
    apply_fused<32><<<gA, b256, 0, stream>>>(Phi, Plo, T32a_h, T32a_l,
                                             A1, 32, 0, 0, 32, T32b_h, T32b_l, 0, 32);
    apply_fused<32><<<gA, b256, 0, stream>>>(Phi, Plo, T32b_h, T32b_l,
                                             A2, 32, 0, 0, 32, T32a_h, T32a_l, 0, 32);
    apply_fused<32><<<gA, b256, 0, stream>>>(Phi, Plo, T32a_h, T32a_l,
                                             nullptr, 0, 0, 0, 0, T32b_h, T32b_l, 0, 32);
    apply_fused<32><<<gA, b256, 0, stream>>>(Phi, Plo, T32b_h, T32b_l,
                                             M0, 96, 0, 0, 32, nullptr, nullptr, 0, 32);

    build_M0<<<dim3(16, NPAIR), b256, 0, stream>>>(A1, A2, M0, T96a_h, T96a_l);

    // ---- M-chain (D=96): M4 = P^4 M0; keep M2 cols 32..63 ----
    apply_fused<96><<<gA, b256, 0, stream>>>(Phi, Plo, T96a_h, T96a_l,
                                             nullptr, 0, 0, 0, 0, T96b_h, T96b_l, 0, 96);
    apply_fused<96><<<gA, b256, 0, stream>>>(Phi, Plo, T96b_h, T96b_l,
                                             M2p, 32, 0, 32, 64, T96a_h, T96a_l, 0, 96);
    apply_fused<96><<<gA, b256, 0, stream>>>(Phi, Plo, T96a_h, T96a_l,
                                             nullptr, 0, 0, 0, 0, T96b_h, T96b_l, 0, 96);
    apply_fused<96><<<gA, b256, 0, stream>>>(Phi, Plo, T96b_h, T96b_l,
                                             M4, 96, 0, 0, 96, T64a_h, T64a_l, 32, 64);

    // ---- N-chain (D=64): Z8 = P^4 (M4 cols 32..95) ----
    apply_fused<64><<<gA, b256, 0, stream>>>(Phi, Plo, T64a_h, T64a_l,
                                             nullptr, 0, 0, 0, 0, T64b_h, T64b_l, 0, 64);
    apply_fused<64><<<gA, b256, 0, stream>>>(Phi, Plo, T64b_h, T64b_l,
                                             nullptr, 0, 0, 0, 0, T64a_h, T64a_l, 0, 64);
    apply_fused<64><<<gA, b256, 0, stream>>>(Phi, Plo, T64a_h, T64a_l,
                                             nullptr, 0, 0, 0, 0, T64b_h, T64b_l, 0, 64);
    apply_fused<64><<<gA, b256, 0, stream>>>(Phi, Plo, T64b_h, T64b_l,
                                             Z8, 64, 0, 0, 64, nullptr, nullptr, 0, 64);

    hipMemsetAsync(out, 0, (size_t)NPAIR * 224 * sizeof(float), stream);
    pool_kernel<<<dim3(7, NPAIR, 8), dim3(32, 8), 0, stream>>>(X, M0, M2p, M4, Z8, out);
}

// Round 5
// 455.078 us; speedup vs baseline: 3.3486x; 1.0755x over previous
//
#include <hip/hip_runtime.h>
#include <math.h>

#define NPTS 1024
#define DIM 32
#define NPAIR 16   // B*NW

typedef __attribute__((ext_vector_type(8))) short short8;
typedef __attribute__((ext_vector_type(4))) float f32x4;
typedef __attribute__((ext_vector_type(8))) unsigned short ushort8v;
typedef __attribute__((ext_vector_type(4))) unsigned short ushort4v;
typedef unsigned short u16;

__device__ __forceinline__ u16 bf16_rne(float v) {
    unsigned u = __float_as_uint(v);
    return (u16)((u + 0x7fffu + ((u >> 16) & 1u)) >> 16);
}
__device__ __forceinline__ float bf16_to_f32(u16 b) {
    return __uint_as_float(((unsigned)b) << 16);
}

// ============ build X + sqX + XT hi/lo (bf16 transposed) ============
// grid (16 ntiles, NPAIR), block 256
__global__ __launch_bounds__(256) void build_X(const float* __restrict__ pc,
                                               const float* __restrict__ alphas,
                                               float* __restrict__ X,
                                               float* __restrict__ sqX,
                                               u16* __restrict__ hiT,
                                               u16* __restrict__ loT) {
    __shared__ float S[DIM][68];
    int pair = blockIdx.y, n0 = blockIdx.x * 64, tid = threadIdx.x;
    int b = pair >> 2, w = pair & 3;
    for (int e = tid; e < 512; e += 256) {
        int e4 = e * 4;
        int dn = e4 >> 5, dq = e4 & 31;
        float4 p = *(const float4*)&pc[((size_t)b * NPTS + n0 + dn) * DIM + dq];
        float4 al = *(const float4*)&alphas[w * DIM + dq];
        float4 x = make_float4(p.x * al.x, p.y * al.y, p.z * al.z, p.w * al.w);
        *(float4*)&X[((size_t)pair * NPTS + n0 + dn) * DIM + dq] = x;
        S[dq][dn] = x.x; S[dq + 1][dn] = x.y; S[dq + 2][dn] = x.z; S[dq + 3][dn] = x.w;
    }
    __syncthreads();
    if (tid < 64) {
        float s = 0.f;
#pragma unroll
        for (int d = 0; d < DIM; d++) { float v = S[d][tid]; s += v * v; }
        sqX[pair * NPTS + n0 + tid] = s;
    }
    for (int idx = tid; idx < DIM * 4; idx += 256) {
        int row = idx >> 2, nq = (idx & 3) * 16;
        ushort8v hv[2], lv[2];
#pragma unroll
        for (int i = 0; i < 16; i++) {
            float v = S[row][nq + i];
            u16 hb = bf16_rne(v);
            hv[i >> 3][i & 7] = hb;
            lv[i >> 3][i & 7] = bf16_rne(v - bf16_to_f32(hb));
        }
        size_t o = ((size_t)pair * DIM + row) * NPTS + n0 + nq;
        *(ushort8v*)(hiT + o) = hv[0]; *(ushort8v*)(hiT + o + 8) = hv[1];
        *(ushort8v*)(loT + o) = lv[0]; *(ushort8v*)(loT + o + 8) = lv[1];
    }
}

// ============ single-pass W: Whi/Wlo bf16 + atomic deg ============
// grid (16 rowtiles, 4 jslices, NPAIR), block 256
__global__ __launch_bounds__(256, 4) void W_kernel(const float* __restrict__ X,
                                                   const float* __restrict__ sqX,
                                                   const float* __restrict__ sigp,
                                                   float* __restrict__ deg,
                                                   u16* __restrict__ Whi,
                                                   u16* __restrict__ Wlo) {
    int pair = blockIdx.z;
    int i0 = blockIdx.x * 64, j0 = blockIdx.y * 256;
    float rsig = -1.0f / (*sigp);
    const float* Xp = X + (size_t)pair * NPTS * DIM;

    __shared__ float XiT[DIM][68];
    __shared__ float XjT[DIM][68];
    __shared__ float sqjS[64];

    int tid = threadIdx.x;
    int cx = tid & 15, ry = tid >> 4;

    {
        int r = tid & 63, dgb = (tid >> 6) * 4;
#pragma unroll
        for (int p = 0; p < 2; p++) {
            int dg = dgb + p * 16;
            float4 v = *(const float4*)&Xp[(size_t)(i0 + r) * DIM + dg];
            XiT[dg][r] = v.x; XiT[dg + 1][r] = v.y; XiT[dg + 2][r] = v.z; XiT[dg + 3][r] = v.w;
        }
    }
    float sqi[4];
#pragma unroll
    for (int a = 0; a < 4; a++) sqi[a] = sqX[pair * NPTS + i0 + ry * 4 + a];

    float rs[4] = {0.f, 0.f, 0.f, 0.f};
#pragma unroll 1
    for (int jt = 0; jt < 256; jt += 64) {
        __syncthreads();
        {
            int r = tid & 63, dgb = (tid >> 6) * 4;
#pragma unroll
            for (int p = 0; p < 2; p++) {
                int dg = dgb + p * 16;
                float4 v = *(const float4*)&Xp[(size_t)(j0 + jt + r) * DIM + dg];
                XjT[dg][r] = v.x; XjT[dg + 1][r] = v.y; XjT[dg + 2][r] = v.z; XjT[dg + 3][r] = v.w;
            }
        }
        if (tid < 64) sqjS[tid] = sqX[pair * NPTS + j0 + jt + tid];
        __syncthreads();

        float dot[4][4] = {};
#pragma unroll
        for (int d = 0; d < DIM; d++) {
            float4 a = *(const float4*)&XiT[d][ry * 4];
            float4 b = *(const float4*)&XjT[d][cx * 4];
            dot[0][0] += a.x * b.x; dot[0][1] += a.x * b.y; dot[0][2] += a.x * b.z; dot[0][3] += a.x * b.w;
            dot[1][0] += a.y * b.x; dot[1][1] += a.y * b.y; dot[1][2] += a.y * b.z; dot[1][3] += a.y * b.w;
            dot[2][0] += a.z * b.x; dot[2][1] += a.z * b.y; dot[2][2] += a.z * b.z; dot[2][3] += a.z * b.w;
            dot[3][0] += a.w * b.x; dot[3][1] += a.w * b.y; dot[3][2] += a.w * b.z; dot[3][3] += a.w * b.w;
        }
#pragma unroll
        for (int a = 0; a < 4; a++) {
            int i = i0 + ry * 4 + a;
            int jb = j0 + jt + cx * 4;
            ushort4v hv, lv;
#pragma unroll
            for (int bb = 0; bb < 4; bb++) {
                float Dm = sqi[a] + sqjS[cx * 4 + bb] - 2.0f * dot[a][bb];
                float K = __expf(Dm * rsig);
                float Wv = (K >= 0.5f) ? K : 0.0f;
                rs[a] += Wv;
                u16 hb = bf16_rne(Wv);
                hv[bb] = hb;
                lv[bb] = bf16_rne(Wv - bf16_to_f32(hb));
            }
            size_t o = ((size_t)pair * NPTS + i) * NPTS + jb;
            *(ushort4v*)(Whi + o) = hv;
            *(ushort4v*)(Wlo + o) = lv;
        }
    }
#pragma unroll
    for (int a = 0; a < 4; a++) {
        float s = rs[a];
        s += __shfl_xor(s, 1); s += __shfl_xor(s, 2);
        s += __shfl_xor(s, 4); s += __shfl_xor(s, 8);
        if (cx == 0) atomicAdd(&deg[pair * NPTS + i0 + ry * 4 + a], s);
    }
}

// ============ fused apply: O = 0.5*Y + (0.5/deg)*(W@Y), bf16x3 MFMA, k-split=8 ============
// grid (32 rowtiles, NPAIR), block 512 (8 waves; wave w owns k-eighth w)
template <int DC>
__global__ __launch_bounds__(512, 4) void apply_fused(const u16* __restrict__ Whi,
                                                      const u16* __restrict__ Wlo,
                                                      const u16* __restrict__ Yhi,
                                                      const u16* __restrict__ Ylo,
                                                      const float* __restrict__ deg,
                                                      const float* __restrict__ prevF,
                                                      int prevStride, int prevOff,
                                                      float* __restrict__ dstF,
                                                      int dstStride, int dstOff,
                                                      float* __restrict__ sliceF,  // cols 32..63 -> stride 32
                                                      u16* __restrict__ hiT, u16* __restrict__ loT,
                                                      int tC0, int tCN) {
    constexpr int NT = DC / 16;
    constexpr int SP = DC + 8;
    __shared__ float S[4][32][SP];
    __shared__ float rdegS[32];
    int pair = blockIdx.y;
    int r0 = blockIdx.x * 32;
    int tid = threadIdx.x;
    int wv = tid >> 6, lane = tid & 63;
    int m = lane & 15, quad = lane >> 4;
    int kb = wv * 128;

    if (tid < 32) rdegS[tid] = 0.5f / deg[pair * NPTS + r0 + tid];

    size_t aoff = ((size_t)pair * NPTS + r0 + m) * NPTS + kb + quad * 8;
    size_t boff = ((size_t)pair * DC + m) * NPTS + kb + quad * 8;

    f32x4 acc[2][NT];
#pragma unroll
    for (int mt = 0; mt < 2; mt++)
#pragma unroll
        for (int nt = 0; nt < NT; nt++)
#pragma unroll
            for (int i = 0; i < 4; i++) acc[mt][nt][i] = 0.0f;

#pragma unroll 2
    for (int c = 0; c < 4; c++) {
        int ko = c * 32;
        short8 a0h = *(const short8*)(Whi + aoff + ko);
        short8 a0l = *(const short8*)(Wlo + aoff + ko);
        short8 a1h = *(const short8*)(Whi + aoff + 16 * NPTS + ko);
        short8 a1l = *(const short8*)(Wlo + aoff + 16 * NPTS + ko);
#pragma unroll
        for (int nt = 0; nt < NT; nt++) {
            short8 bh = *(const short8*)(Yhi + boff + (size_t)nt * 16 * NPTS + ko);
            short8 bl = *(const short8*)(Ylo + boff + (size_t)nt * 16 * NPTS + ko);
            acc[0][nt] = __builtin_amdgcn_mfma_f32_16x16x32_bf16(a0h, bh, acc[0][nt], 0, 0, 0);
            acc[0][nt] = __builtin_amdgcn_mfma_f32_16x16x32_bf16(a0l, bh, acc[0][nt], 0, 0, 0);
            acc[0][nt] = __builtin_amdgcn_mfma_f32_16x16x32_bf16(a0h, bl, acc[0][nt], 0, 0, 0);
            acc[1][nt] = __builtin_amdgcn_mfma_f32_16x16x32_bf16(a1h, bh, acc[1][nt], 0, 0, 0);
            acc[1][nt] = __builtin_amdgcn_mfma_f32_16x16x32_bf16(a1l, bh, acc[1][nt], 0, 0, 0);
            acc[1][nt] = __builtin_amdgcn_mfma_f32_16x16x32_bf16(a1h, bl, acc[1][nt], 0, 0, 0);
        }
    }

    // phase 1a: waves 0-3 deposit their partial tiles
    if (wv < 4) {
#pragma unroll
        for (int mt = 0; mt < 2; mt++)
#pragma unroll
            for (int nt = 0; nt < NT; nt++)
#pragma unroll
                for (int i = 0; i < 4; i++)
                    S[wv][mt * 16 + quad * 4 + i][nt * 16 + m] = acc[mt][nt][i];
    }
    __syncthreads();
    // phase 1b: waves 4-7 add into planes 0-3 (cells are lane-unique per plane)
    if (wv >= 4) {
#pragma unroll
        for (int mt = 0; mt < 2; mt++)
#pragma unroll
            for (int nt = 0; nt < NT; nt++)
#pragma unroll
                for (int i = 0; i < 4; i++)
                    S[wv - 4][mt * 16 + quad * 4 + i][nt * 16 + m] += acc[mt][nt][i];
    }
    __syncthreads();

    // phase 2: sum 4 planes, epilogue O = 0.5*prev + rdeg*sum, write fp32, stash in S[0]
    constexpr int E2 = 32 * DC / 4;
    for (int e = tid; e < E2; e += 512) {
        int e4 = e * 4;
        int n = e4 / DC, d = e4 % DC;
        float4 s0 = *(const float4*)&S[0][n][d];
        float4 s1 = *(const float4*)&S[1][n][d];
        float4 s2 = *(const float4*)&S[2][n][d];
        float4 s3 = *(const float4*)&S[3][n][d];
        float4 pv = *(const float4*)&prevF[((size_t)pair * NPTS + r0 + n) * prevStride + prevOff + d];
        float r = rdegS[n];
        float4 o = make_float4(0.5f * pv.x + r * (s0.x + s1.x + s2.x + s3.x),
                               0.5f * pv.y + r * (s0.y + s1.y + s2.y + s3.y),
                               0.5f * pv.z + r * (s0.z + s1.z + s2.z + s3.z),
                               0.5f * pv.w + r * (s0.w + s1.w + s2.w + s3.w));
        *(float4*)&dstF[((size_t)pair * NPTS + r0 + n) * dstStride + dstOff + d] = o;
        if (sliceF && d >= 32 && d < 64)
            *(float4*)&sliceF[((size_t)pair * NPTS + r0 + n) * 32 + (d - 32)] = o;
        *(float4*)&S[0][n][d] = o;
    }
    __syncthreads();

    // phase 3: transposed bf16 hi/lo operand for the next step
    if (hiT) {
        for (int e = tid; e < tCN * 4; e += 512) {
            int row = e >> 2, nq = (e & 3) * 8;
            ushort8v hv, lv;
#pragma unroll
            for (int j = 0; j < 8; j++) {
                float v = S[0][nq + j][tC0 + row];
                u16 hb = bf16_rne(v);
                hv[j] = hb;
                lv[j] = bf16_rne(v - bf16_to_f32(hb));
            }
            size_t o = ((size_t)pair * tCN + row) * NPTS + r0 + nq;
            *(ushort8v*)(hiT + o) = hv;
            *(ushort8v*)(loT + o) = lv;
        }
    }
}

// ============ build M0 cols 32..95 fp32 + full M0T hi/lo ============
// grid (16 ntiles, NPAIR), block 256
__global__ __launch_bounds__(256) void build_M0(const float* __restrict__ A1,
                                                const float* __restrict__ A2,
                                                float* __restrict__ M0,
                                                u16* __restrict__ hiT,
                                                u16* __restrict__ loT) {
    __shared__ float S[96][68];
    int pair = blockIdx.y, n0 = blockIdx.x * 64, tid = threadIdx.x;
    for (int e = tid; e < 512; e += 256) {
        int e4 = e * 4;
        int dn = e4 >> 5, dq = e4 & 31;
        size_t pn = (size_t)pair * NPTS + n0 + dn;
        float4 a1 = *(const float4*)&A1[pn * 32 + dq];
        float4 a2 = *(const float4*)&A2[pn * 32 + dq];
        float4 t4 = *(const float4*)&M0[pn * 96 + dq];
        float4 f0 = make_float4(fabsf(a1.x - a2.x), fabsf(a1.y - a2.y), fabsf(a1.z - a2.z), fabsf(a1.w - a2.w));
        float4 f1 = make_float4(fabsf(a2.x - t4.x), fabsf(a2.y - t4.y), fabsf(a2.z - t4.z), fabsf(a2.w - t4.w));
        *(float4*)&M0[pn * 96 + 32 + dq] = f0;
        *(float4*)&M0[pn * 96 + 64 + dq] = f1;
        S[dq][dn] = t4.x; S[dq + 1][dn] = t4.y; S[dq + 2][dn] = t4.z; S[dq + 3][dn] = t4.w;
        S[32 + dq][dn] = f0.x; S[33 + dq][dn] = f0.y; S[34 + dq][dn] = f0.z; S[35 + dq][dn] = f0.w;
        S[64 + dq][dn] = f1.x; S[65 + dq][dn] = f1.y; S[66 + dq][dn] = f1.z; S[67 + dq][dn] = f1.w;
    }
    __syncthreads();
    for (int idx = tid; idx < 96 * 4; idx += 256) {
        int row = idx >> 2, nq = (idx & 3) * 16;
        ushort8v hv[2], lv[2];
#pragma unroll
        for (int i = 0; i < 16; i++) {
            float v = S[row][nq + i];
            u16 hb = bf16_rne(v);
            hv[i >> 3][i & 7] = hb;
            lv[i >> 3][i & 7] = bf16_rne(v - bf16_to_f32(hb));
        }
        size_t o = ((size_t)pair * 96 + row) * NPTS + n0 + nq;
        *(ushort8v*)(hiT + o) = hv[0]; *(ushort8v*)(hiT + o + 8) = hv[1];
        *(ushort8v*)(loT + o) = lv[0]; *(ushort8v*)(loT + o + 8) = lv[1];
    }
}

// ============ pooling: grid (7, NPAIR, 8 nslices), block (32,8), atomic accumulate ============
__global__ __launch_bounds__(256) void pool_kernel(const float* __restrict__ X,
                                                   const float* __restrict__ M0,
                                                   const float* __restrict__ M2p,
                                                   const float* __restrict__ M4,
                                                   const float* __restrict__ Z8,
                                                   float* __restrict__ out) {
    int g = blockIdx.x;
    int pair = blockIdx.y;
    int sl = blockIdx.z;
    int d = threadIdx.x;
    int ty = threadIdx.y;
    float s = 0.0f;
    int nend = sl * 128 + 128;
    for (int n = sl * 128 + ty; n < nend; n += 8) {
        size_t pn = (size_t)pair * NPTS + n;
        float v = 0.0f;
        switch (g) {
            case 0: v = X[pn * 32 + d]; break;
            case 1: v = M0[pn * 96 + 32 + d]; break;
            case 2: v = M0[pn * 96 + 64 + d]; break;
            case 3: v = fabsf(M0[pn * 96 + d] - M4[pn * 96 + d]); break;
            case 4: v = fabsf(M2p[pn * 32 + d] - M4[pn * 96 + 32 + d]); break;
            case 5: v = fabsf(M4[pn * 96 + 32 + d] - Z8[pn * 64 + d]); break;
            case 6: v = fabsf(M4[pn * 96 + 64 + d] - Z8[pn * 64 + 32 + d]); break;
        }
        s += v;
    }
    __shared__ float red[8][33];
    red[ty][d] = s;
    __syncthreads();
    if (ty == 0) {
        float tot = 0.0f;
#pragma unroll
        for (int t = 0; t < 8; t++) tot += red[t][d];
        atomicAdd(&out[(size_t)pair * 224 + g * 32 + d], tot * (1.0f / 1024.0f));
    }
}

extern "C" void kernel_launch(void* const* d_in, const int* in_sizes, int n_in,
                              void* d_out, int out_size, void* d_ws, size_t ws_size,
                              hipStream_t stream) {
    const float* pc     = (const float*)d_in[0];
    const float* alphas = (const float*)d_in[1];
    const float* sigp   = (const float*)d_in[2];
    float* out = (float*)d_out;
    float* ws = (float*)d_ws;

    // ---- workspace layout (~116 MB) ----
    float* X    = ws;                         // 524288
    float* sqX  = X + 524288;                 // 16384
    float* deg  = sqX + 16384;                // 16384
    u16* Whi = (u16*)(deg + 16384);           // 16777216 u16
    u16* Wlo = Whi + 16777216;                // 16777216 u16
    // region overlaid by F96b during M/N chains:
    float* A1   = (float*)(Wlo + 16777216);   // 524288
    float* A2   = A1 + 524288;                // 524288
    u16* T32a_h = (u16*)(A2 + 524288);        // 524288 u16 each
    u16* T32a_l = T32a_h + 524288;
    u16* T32b_h = T32a_l + 524288;
    u16* T32b_l = T32b_h + 524288;
    float* F96b = A1;                         // 1572864 floats overlay (A1,A2,T32a_h/l dead)
    // ----
    float* M0   = (float*)(T32b_l + 524288);  // 1572864
    float* M2p  = M0 + 1572864;               // 524288 (cols 32..63 of M2)
    float* M4f  = M2p + 524288;               // 1572864
    float* Z8   = M4f + 1572864;              // 1048576
    float* F96a = Z8 + 1048576;               // 1572864  (also A3 overlay before M-chain)
    float* A3   = F96a;
    u16* T96a_h = (u16*)(F96a + 1572864);     // 1572864 u16 each
    u16* T96a_l = T96a_h + 1572864;
    u16* T96b_h = T96a_l + 1572864;
    u16* T96b_l = T96b_h + 1572864;
    // T64 overlays (T96 dead when N-chain runs)
    u16* T64a_h = T96a_h;
    u16* T64a_l = T96a_l;
    u16* T64b_h = T96b_h;
    u16* T64b_l = T96b_l;

    dim3 b256(256), b512(512);
    dim3 gA(32, NPAIR);

    build_X<<<dim3(16, NPAIR), b256, 0, stream>>>(pc, alphas, X, sqX, T32a_h, T32a_l);
    hipMemsetAsync(deg, 0, 16384 * sizeof(float), stream);
    W_kernel<<<dim3(16, 4, NPAIR), b256, 0, stream>>>(X, sqX, sigp, deg, Whi, Wlo);

    // ---- A-chain (D=32): A1, A2, A3, A4 -> M0 cols 0..31 ----
    apply_fused<32><<<gA, b512, 0, stream>>>(Whi, Wlo, T32a_h, T32a_l, deg,
                                             X, 32, 0, A1, 32, 0, nullptr, T32b_h, T32b_l, 0, 32);
    apply_fused<32><<<gA, b512, 0, stream>>>(Whi, Wlo, T32b_h, T32b_l, deg,
                                             A1, 32, 0, A2, 32, 0, nullptr, T32a_h, T32a_l, 0, 32);
    apply_fused<32><<<gA, b512, 0, stream>>>(Whi, Wlo, T32a_h, T32a_l, deg,
                                             A2, 32, 0, A3, 32, 0, nullptr, T32b_h, T32b_l, 0, 32);
    apply_fused<32><<<gA, b512, 0, stream>>>(Whi, Wlo, T32b_h, T32b_l, deg,
                                             A3, 32, 0, M0, 96, 0, nullptr, nullptr, nullptr, 0, 32);

    build_M0<<<dim3(16, NPAIR), b256, 0, stream>>>(A1, A2, M0, T96a_h, T96a_l);

    // ---- M-chain (D=96): M4 = P^4 M0; M2 cols 32..63 saved to M2p ----
    apply_fused<96><<<gA, b512, 0, stream>>>(Whi, Wlo, T96a_h, T96a_l, deg,
                                             M0, 96, 0, F96a, 96, 0, nullptr, T96b_h, T96b_l, 0, 96);
    apply_fused<96><<<gA, b512, 0, stream>>>(Whi, Wlo, T96b_h, T96b_l, deg,
                                             F96a, 96, 0, F96b, 96, 0, M2p, T96a_h, T96a_l, 0, 96);
    apply_fused<96><<<gA, b512, 0, stream>>>(Whi, Wlo, T96a_h, T96a_l, deg,
                                             F96b, 96, 0, F96a, 96, 0, nullptr, T96b_h, T96b_l, 0, 96);
    apply_fused<96><<<gA, b512, 0, stream>>>(Whi, Wlo, T96b_h, T96b_l, deg,
                                             F96a, 96, 0, M4f, 96, 0, nullptr, T64a_h, T64a_l, 32, 64);

    // ---- N-chain (D=64): Z8 = P^4 (M4 cols 32..95) ----
    apply_fused<64><<<gA, b512, 0, stream>>>(Whi, Wlo, T64a_h, T64a_l, deg,
                                             M4f, 96, 32, F96a, 64, 0, nullptr, T64b_h, T64b_l, 0, 64);
    apply_fused<64><<<gA, b512, 0, stream>>>(Whi, Wlo, T64b_h, T64b_l, deg,
                                             F96a, 64, 0, F96b, 64, 0, nullptr, T64a_h, T64a_l, 0, 64);
    apply_fused<64><<<gA, b512, 0, stream>>>(Whi, Wlo, T64a_h, T64a_l, deg,
                                             F96b, 64, 0, F96a, 64, 0, nullptr, T64b_h, T64b_l, 0, 64);
    apply_fused<64><<<gA, b512, 0, stream>>>(Whi, Wlo, T64b_h, T64b_l, deg,
                                             F96a, 64, 0, Z8, 64, 0, nullptr, nullptr, nullptr, 0, 64);

    hipMemsetAsync(out, 0, (size_t)NPAIR * 224 * sizeof(float), stream);
    pool_kernel<<<dim3(7, NPAIR, 8), dim3(32, 8), 0, stream>>>(X, M0, M2p, M4f, Z8, out);
}

// Round 6
// 381.213 us; speedup vs baseline: 3.9974x; 1.1938x over previous
//
#include <hip/hip_runtime.h>
#include <math.h>

#define NPTS 1024
#define DIM 32
#define NPAIR 16   // B*NW

typedef __attribute__((ext_vector_type(8))) short short8;
typedef __attribute__((ext_vector_type(4))) float f32x4;
typedef __attribute__((ext_vector_type(8))) unsigned short ushort8v;
typedef __attribute__((ext_vector_type(4))) unsigned short ushort4v;
typedef unsigned short u16;

__device__ __forceinline__ u16 bf16_rne(float v) {
    unsigned u = __float_as_uint(v);
    return (u16)((u + 0x7fffu + ((u >> 16) & 1u)) >> 16);
}
__device__ __forceinline__ float bf16_to_f32(u16 b) {
    return __uint_as_float(((unsigned)b) << 16);
}

// ============ build X + sqX + XT hi/lo (bf16 transposed) ============
// grid (16 ntiles, NPAIR), block 256
__global__ __launch_bounds__(256) void build_X(const float* __restrict__ pc,
                                               const float* __restrict__ alphas,
                                               float* __restrict__ X,
                                               float* __restrict__ sqX,
                                               u16* __restrict__ hiT,
                                               u16* __restrict__ loT) {
    __shared__ float S[DIM][68];
    int pair = blockIdx.y, n0 = blockIdx.x * 64, tid = threadIdx.x;
    int b = pair >> 2, w = pair & 3;
    for (int e = tid; e < 512; e += 256) {
        int e4 = e * 4;
        int dn = e4 >> 5, dq = e4 & 31;
        float4 p = *(const float4*)&pc[((size_t)b * NPTS + n0 + dn) * DIM + dq];
        float4 al = *(const float4*)&alphas[w * DIM + dq];
        float4 x = make_float4(p.x * al.x, p.y * al.y, p.z * al.z, p.w * al.w);
        *(float4*)&X[((size_t)pair * NPTS + n0 + dn) * DIM + dq] = x;
        S[dq][dn] = x.x; S[dq + 1][dn] = x.y; S[dq + 2][dn] = x.z; S[dq + 3][dn] = x.w;
    }
    __syncthreads();
    if (tid < 64) {
        float s = 0.f;
#pragma unroll
        for (int d = 0; d < DIM; d++) { float v = S[d][tid]; s += v * v; }
        sqX[pair * NPTS + n0 + tid] = s;
    }
    for (int idx = tid; idx < DIM * 4; idx += 256) {
        int row = idx >> 2, nq = (idx & 3) * 16;
        ushort8v hv[2], lv[2];
#pragma unroll
        for (int i = 0; i < 16; i++) {
            float v = S[row][nq + i];
            u16 hb = bf16_rne(v);
            hv[i >> 3][i & 7] = hb;
            lv[i >> 3][i & 7] = bf16_rne(v - bf16_to_f32(hb));
        }
        size_t o = ((size_t)pair * DIM + row) * NPTS + n0 + nq;
        *(ushort8v*)(hiT + o) = hv[0]; *(ushort8v*)(hiT + o + 8) = hv[1];
        *(ushort8v*)(loT + o) = lv[0]; *(ushort8v*)(loT + o + 8) = lv[1];
    }
}

// ============ single-pass W: W bf16 (single) + atomic deg ============
// grid (16 rowtiles, 4 jslices, NPAIR), block 256
__global__ __launch_bounds__(256, 4) void W_kernel(const float* __restrict__ X,
                                                   const float* __restrict__ sqX,
                                                   const float* __restrict__ sigp,
                                                   float* __restrict__ deg,
                                                   u16* __restrict__ Whi) {
    int pair = blockIdx.z;
    int i0 = blockIdx.x * 64, j0 = blockIdx.y * 256;
    float rsig = -1.0f / (*sigp);
    const float* Xp = X + (size_t)pair * NPTS * DIM;

    __shared__ float XiT[DIM][68];
    __shared__ float XjT[DIM][68];
    __shared__ float sqjS[64];

    int tid = threadIdx.x;
    int cx = tid & 15, ry = tid >> 4;

    {
        int r = tid & 63, dgb = (tid >> 6) * 4;
#pragma unroll
        for (int p = 0; p < 2; p++) {
            int dg = dgb + p * 16;
            float4 v = *(const float4*)&Xp[(size_t)(i0 + r) * DIM + dg];
            XiT[dg][r] = v.x; XiT[dg + 1][r] = v.y; XiT[dg + 2][r] = v.z; XiT[dg + 3][r] = v.w;
        }
    }
    float sqi[4];
#pragma unroll
    for (int a = 0; a < 4; a++) sqi[a] = sqX[pair * NPTS + i0 + ry * 4 + a];

    float rs[4] = {0.f, 0.f, 0.f, 0.f};
#pragma unroll 1
    for (int jt = 0; jt < 256; jt += 64) {
        __syncthreads();
        {
            int r = tid & 63, dgb = (tid >> 6) * 4;
#pragma unroll
            for (int p = 0; p < 2; p++) {
                int dg = dgb + p * 16;
                float4 v = *(const float4*)&Xp[(size_t)(j0 + jt + r) * DIM + dg];
                XjT[dg][r] = v.x; XjT[dg + 1][r] = v.y; XjT[dg + 2][r] = v.z; XjT[dg + 3][r] = v.w;
            }
        }
        if (tid < 64) sqjS[tid] = sqX[pair * NPTS + j0 + jt + tid];
        __syncthreads();

        float dot[4][4] = {};
#pragma unroll
        for (int d = 0; d < DIM; d++) {
            float4 a = *(const float4*)&XiT[d][ry * 4];
            float4 b = *(const float4*)&XjT[d][cx * 4];
            dot[0][0] += a.x * b.x; dot[0][1] += a.x * b.y; dot[0][2] += a.x * b.z; dot[0][3] += a.x * b.w;
            dot[1][0] += a.y * b.x; dot[1][1] += a.y * b.y; dot[1][2] += a.y * b.z; dot[1][3] += a.y * b.w;
            dot[2][0] += a.z * b.x; dot[2][1] += a.z * b.y; dot[2][2] += a.z * b.z; dot[2][3] += a.z * b.w;
            dot[3][0] += a.w * b.x; dot[3][1] += a.w * b.y; dot[3][2] += a.w * b.z; dot[3][3] += a.w * b.w;
        }
#pragma unroll
        for (int a = 0; a < 4; a++) {
            int i = i0 + ry * 4 + a;
            int jb = j0 + jt + cx * 4;
            ushort4v hv;
#pragma unroll
            for (int bb = 0; bb < 4; bb++) {
                float Dm = sqi[a] + sqjS[cx * 4 + bb] - 2.0f * dot[a][bb];
                float K = __expf(Dm * rsig);
                float Wv = (K >= 0.5f) ? K : 0.0f;
                rs[a] += Wv;
                hv[bb] = bf16_rne(Wv);
            }
            *(ushort4v*)(Whi + ((size_t)pair * NPTS + i) * NPTS + jb) = hv;
        }
    }
#pragma unroll
    for (int a = 0; a < 4; a++) {
        float s = rs[a];
        s += __shfl_xor(s, 1); s += __shfl_xor(s, 2);
        s += __shfl_xor(s, 4); s += __shfl_xor(s, 8);
        if (cx == 0) atomicAdd(&deg[pair * NPTS + i0 + ry * 4 + a], s);
    }
}

// ============ fused apply: O = 0.5*Y + (0.5/deg)*(W@Y); W bf16, Y bf16 hi/lo; k-split=8 ============
// grid (32 rowtiles, NPAIR), block 512 (8 waves; wave w owns k-eighth w)
template <int DC>
__global__ __launch_bounds__(512, 4) void apply_fused(const u16* __restrict__ Whi,
                                                      const u16* __restrict__ Yhi,
                                                      const u16* __restrict__ Ylo,
                                                      const float* __restrict__ deg,
                                                      const float* __restrict__ prevF,
                                                      int prevStride, int prevOff,
                                                      float* __restrict__ dstF,
                                                      int dstStride, int dstOff,
                                                      float* __restrict__ sliceF,  // cols 32..63 -> stride 32
                                                      u16* __restrict__ hiT, u16* __restrict__ loT,
                                                      int tC0, int tCN) {
    constexpr int NT = DC / 16;
    constexpr int SP = DC + 8;
    __shared__ float S[4][32][SP];
    __shared__ float rdegS[32];
    int pair = blockIdx.y;
    int r0 = blockIdx.x * 32;
    int tid = threadIdx.x;
    int wv = tid >> 6, lane = tid & 63;
    int m = lane & 15, quad = lane >> 4;
    int kb = wv * 128;

    if (tid < 32) rdegS[tid] = 0.5f / deg[pair * NPTS + r0 + tid];

    size_t aoff = ((size_t)pair * NPTS + r0 + m) * NPTS + kb + quad * 8;
    size_t boff = ((size_t)pair * DC + m) * NPTS + kb + quad * 8;

    f32x4 acc[2][NT];
#pragma unroll
    for (int mt = 0; mt < 2; mt++)
#pragma unroll
        for (int nt = 0; nt < NT; nt++)
#pragma unroll
            for (int i = 0; i < 4; i++) acc[mt][nt][i] = 0.0f;

#pragma unroll 2
    for (int c = 0; c < 4; c++) {
        int ko = c * 32;
        short8 a0h = *(const short8*)(Whi + aoff + ko);
        short8 a1h = *(const short8*)(Whi + aoff + 16 * NPTS + ko);
#pragma unroll
        for (int nt = 0; nt < NT; nt++) {
            short8 bh = *(const short8*)(Yhi + boff + (size_t)nt * 16 * NPTS + ko);
            short8 bl = *(const short8*)(Ylo + boff + (size_t)nt * 16 * NPTS + ko);
            acc[0][nt] = __builtin_amdgcn_mfma_f32_16x16x32_bf16(a0h, bh, acc[0][nt], 0, 0, 0);
            acc[0][nt] = __builtin_amdgcn_mfma_f32_16x16x32_bf16(a0h, bl, acc[0][nt], 0, 0, 0);
            acc[1][nt] = __builtin_amdgcn_mfma_f32_16x16x32_bf16(a1h, bh, acc[1][nt], 0, 0, 0);
            acc[1][nt] = __builtin_amdgcn_mfma_f32_16x16x32_bf16(a1h, bl, acc[1][nt], 0, 0, 0);
        }
    }

    // phase 1a: waves 0-3 deposit their partial tiles
    if (wv < 4) {
#pragma unroll
        for (int mt = 0; mt < 2; mt++)
#pragma unroll
            for (int nt = 0; nt < NT; nt++)
#pragma unroll
                for (int i = 0; i < 4; i++)
                    S[wv][mt * 16 + quad * 4 + i][nt * 16 + m] = acc[mt][nt][i];
    }
    __syncthreads();
    // phase 1b: waves 4-7 add into planes 0-3
    if (wv >= 4) {
#pragma unroll
        for (int mt = 0; mt < 2; mt++)
#pragma unroll
            for (int nt = 0; nt < NT; nt++)
#pragma unroll
                for (int i = 0; i < 4; i++)
                    S[wv - 4][mt * 16 + quad * 4 + i][nt * 16 + m] += acc[mt][nt][i];
    }
    __syncthreads();

    // phase 2: sum planes, epilogue O = 0.5*prev + rdeg*sum, write fp32, stash in S[0]
    constexpr int E2 = 32 * DC / 4;
    for (int e = tid; e < E2; e += 512) {
        int e4 = e * 4;
        int n = e4 / DC, d = e4 % DC;
        float4 s0 = *(const float4*)&S[0][n][d];
        float4 s1 = *(const float4*)&S[1][n][d];
        float4 s2 = *(const float4*)&S[2][n][d];
        float4 s3 = *(const float4*)&S[3][n][d];
        float4 pv = *(const float4*)&prevF[((size_t)pair * NPTS + r0 + n) * prevStride + prevOff + d];
        float r = rdegS[n];
        float4 o = make_float4(0.5f * pv.x + r * (s0.x + s1.x + s2.x + s3.x),
                               0.5f * pv.y + r * (s0.y + s1.y + s2.y + s3.y),
                               0.5f * pv.z + r * (s0.z + s1.z + s2.z + s3.z),
                               0.5f * pv.w + r * (s0.w + s1.w + s2.w + s3.w));
        *(float4*)&dstF[((size_t)pair * NPTS + r0 + n) * dstStride + dstOff + d] = o;
        if (sliceF && d >= 32 && d < 64)
            *(float4*)&sliceF[((size_t)pair * NPTS + r0 + n) * 32 + (d - 32)] = o;
        *(float4*)&S[0][n][d] = o;
    }
    __syncthreads();

    // phase 3: transposed bf16 hi/lo operand for the next step
    if (hiT) {
        for (int e = tid; e < tCN * 4; e += 512) {
            int row = e >> 2, nq = (e & 3) * 8;
            ushort8v hv, lv;
#pragma unroll
            for (int j = 0; j < 8; j++) {
                float v = S[0][nq + j][tC0 + row];
                u16 hb = bf16_rne(v);
                hv[j] = hb;
                lv[j] = bf16_rne(v - bf16_to_f32(hb));
            }
            size_t o = ((size_t)pair * tCN + row) * NPTS + r0 + nq;
            *(ushort8v*)(hiT + o) = hv;
            *(ushort8v*)(loT + o) = lv;
        }
    }
}

// ============ build M0 cols 32..95 fp32 + full M0T hi/lo ============
// grid (16 ntiles, NPAIR), block 256
__global__ __launch_bounds__(256) void build_M0(const float* __restrict__ A1,
                                                const float* __restrict__ A2,
                                                float* __restrict__ M0,
                                                u16* __restrict__ hiT,
                                                u16* __restrict__ loT) {
    __shared__ float S[96][68];
    int pair = blockIdx.y, n0 = blockIdx.x * 64, tid = threadIdx.x;
    for (int e = tid; e < 512; e += 256) {
        int e4 = e * 4;
        int dn = e4 >> 5, dq = e4 & 31;
        size_t pn = (size_t)pair * NPTS + n0 + dn;
        float4 a1 = *(const float4*)&A1[pn * 32 + dq];
        float4 a2 = *(const float4*)&A2[pn * 32 + dq];
        float4 t4 = *(const float4*)&M0[pn * 96 + dq];
        float4 f0 = make_float4(fabsf(a1.x - a2.x), fabsf(a1.y - a2.y), fabsf(a1.z - a2.z), fabsf(a1.w - a2.w));
        float4 f1 = make_float4(fabsf(a2.x - t4.x), fabsf(a2.y - t4.y), fabsf(a2.z - t4.z), fabsf(a2.w - t4.w));
        *(float4*)&M0[pn * 96 + 32 + dq] = f0;
        *(float4*)&M0[pn * 96 + 64 + dq] = f1;
        S[dq][dn] = t4.x; S[dq + 1][dn] = t4.y; S[dq + 2][dn] = t4.z; S[dq + 3][dn] = t4.w;
        S[32 + dq][dn] = f0.x; S[33 + dq][dn] = f0.y; S[34 + dq][dn] = f0.z; S[35 + dq][dn] = f0.w;
        S[64 + dq][dn] = f1.x; S[65 + dq][dn] = f1.y; S[66 + dq][dn] = f1.z; S[67 + dq][dn] = f1.w;
    }
    __syncthreads();
    for (int idx = tid; idx < 96 * 4; idx += 256) {
        int row = idx >> 2, nq = (idx & 3) * 16;
        ushort8v hv[2], lv[2];
#pragma unroll
        for (int i = 0; i < 16; i++) {
            float v = S[row][nq + i];
            u16 hb = bf16_rne(v);
            hv[i >> 3][i & 7] = hb;
            lv[i >> 3][i & 7] = bf16_rne(v - bf16_to_f32(hb));
        }
        size_t o = ((size_t)pair * 96 + row) * NPTS + n0 + nq;
        *(ushort8v*)(hiT + o) = hv[0]; *(ushort8v*)(hiT + o + 8) = hv[1];
        *(ushort8v*)(loT + o) = lv[0]; *(ushort8v*)(loT + o + 8) = lv[1];
    }
}

// ============ pooling: grid (7, NPAIR, 8 nslices), block (32,8), atomic accumulate ============
__global__ __launch_bounds__(256) void pool_kernel(const float* __restrict__ X,
                                                   const float* __restrict__ M0,
                                                   const float* __restrict__ M2p,
                                                   const float* __restrict__ M4,
                                                   const float* __restrict__ Z8,
                                                   float* __restrict__ out) {
    int g = blockIdx.x;
    int pair = blockIdx.y;
    int sl = blockIdx.z;
    int d = threadIdx.x;
    int ty = threadIdx.y;
    float s = 0.0f;
    int nend = sl * 128 + 128;
    for (int n = sl * 128 + ty; n < nend; n += 8) {
        size_t pn = (size_t)pair * NPTS + n;
        float v = 0.0f;
        switch (g) {
            case 0: v = X[pn * 32 + d]; break;
            case 1: v = M0[pn * 96 + 32 + d]; break;
            case 2: v = M0[pn * 96 + 64 + d]; break;
            case 3: v = fabsf(M0[pn * 96 + d] - M4[pn * 96 + d]); break;
            case 4: v = fabsf(M2p[pn * 32 + d] - M4[pn * 96 + 32 + d]); break;
            case 5: v = fabsf(M4[pn * 96 + 32 + d] - Z8[pn * 64 + d]); break;
            case 6: v = fabsf(M4[pn * 96 + 64 + d] - Z8[pn * 64 + 32 + d]); break;
        }
        s += v;
    }
    __shared__ float red[8][33];
    red[ty][d] = s;
    __syncthreads();
    if (ty == 0) {
        float tot = 0.0f;
#pragma unroll
        for (int t = 0; t < 8; t++) tot += red[t][d];
        atomicAdd(&out[(size_t)pair * 224 + g * 32 + d], tot * (1.0f / 1024.0f));
    }
}

extern "C" void kernel_launch(void* const* d_in, const int* in_sizes, int n_in,
                              void* d_out, int out_size, void* d_ws, size_t ws_size,
                              hipStream_t stream) {
    const float* pc     = (const float*)d_in[0];
    const float* alphas = (const float*)d_in[1];
    const float* sigp   = (const float*)d_in[2];
    float* out = (float*)d_out;
    float* ws = (float*)d_ws;

    // ---- workspace layout (~84 MB) ----
    float* X    = ws;                         // 524288
    float* sqX  = X + 524288;                 // 16384
    float* deg  = sqX + 16384;                // 16384
    u16* Whi = (u16*)(deg + 16384);           // 16777216 u16
    // region overlaid by F96b during M/N chains:
    float* A1   = (float*)(Whi + 16777216);   // 524288
    float* A2   = A1 + 524288;                // 524288
    u16* T32a_h = (u16*)(A2 + 524288);        // 524288 u16 each
    u16* T32a_l = T32a_h + 524288;
    u16* T32b_h = T32a_l + 524288;
    u16* T32b_l = T32b_h + 524288;
    float* F96b = A1;                         // 1572864 floats overlay (A1,A2,T32a_h/l dead)
    // ----
    float* M0   = (float*)(T32b_l + 524288);  // 1572864
    float* M2p  = M0 + 1572864;               // 524288 (cols 32..63 of M2)
    float* M4f  = M2p + 524288;               // 1572864
    float* Z8   = M4f + 1572864;              // 1048576
    float* F96a = Z8 + 1048576;               // 1572864  (also A3 overlay before M-chain)
    float* A3   = F96a;
    u16* T96a_h = (u16*)(F96a + 1572864);     // 1572864 u16 each
    u16* T96a_l = T96a_h + 1572864;
    u16* T96b_h = T96a_l + 1572864;
    u16* T96b_l = T96b_h + 1572864;
    u16* T64a_h = T96a_h;
    u16* T64a_l = T96a_l;
    u16* T64b_h = T96b_h;
    u16* T64b_l = T96b_l;

    dim3 b256(256), b512(512);
    dim3 gA(32, NPAIR);

    build_X<<<dim3(16, NPAIR), b256, 0, stream>>>(pc, alphas, X, sqX, T32a_h, T32a_l);
    hipMemsetAsync(deg, 0, 16384 * sizeof(float), stream);
    W_kernel<<<dim3(16, 4, NPAIR), b256, 0, stream>>>(X, sqX, sigp, deg, Whi);

    // ---- A-chain (D=32): A1, A2, A3, A4 -> M0 cols 0..31 ----
    apply_fused<32><<<gA, b512, 0, stream>>>(Whi, T32a_h, T32a_l, deg,
                                             X, 32, 0, A1, 32, 0, nullptr, T32b_h, T32b_l, 0, 32);
    apply_fused<32><<<gA, b512, 0, stream>>>(Whi, T32b_h, T32b_l, deg,
                                             A1, 32, 0, A2, 32, 0, nullptr, T32a_h, T32a_l, 0, 32);
    apply_fused<32><<<gA, b512, 0, stream>>>(Whi, T32a_h, T32a_l, deg,
                                             A2, 32, 0, A3, 32, 0, nullptr, T32b_h, T32b_l, 0, 32);
    apply_fused<32><<<gA, b512, 0, stream>>>(Whi, T32b_h, T32b_l, deg,
                                             A3, 32, 0, M0, 96, 0, nullptr, nullptr, nullptr, 0, 32);

    build_M0<<<dim3(16, NPAIR), b256, 0, stream>>>(A1, A2, M0, T96a_h, T96a_l);

    // ---- M-chain (D=96): M4 = P^4 M0; M2 cols 32..63 saved to M2p ----
    apply_fused<96><<<gA, b512, 0, stream>>>(Whi, T96a_h, T96a_l, deg,
                                             M0, 96, 0, F96a, 96, 0, nullptr, T96b_h, T96b_l, 0, 96);
    apply_fused<96><<<gA, b512, 0, stream>>>(Whi, T96b_h, T96b_l, deg,
                                             F96a, 96, 0, F96b, 96, 0, M2p, T96a_h, T96a_l, 0, 96);
    apply_fused<96><<<gA, b512, 0, stream>>>(Whi, T96a_h, T96a_l, deg,
                                             F96b, 96, 0, F96a, 96, 0, nullptr, T96b_h, T96b_l, 0, 96);
    apply_fused<96><<<gA, b512, 0, stream>>>(Whi, T96b_h, T96b_l, deg,
                                             F96a, 96, 0, M4f, 96, 0, nullptr, T64a_h, T64a_l, 32, 64);

    // ---- N-chain (D=64): Z8 = P^4 (M4 cols 32..95) ----
    apply_fused<64><<<gA, b512, 0, stream>>>(Whi, T64a_h, T64a_l, deg,
                                             M4f, 96, 32, F96a, 64, 0, nullptr, T64b_h, T64b_l, 0, 64);
    apply_fused<64><<<gA, b512, 0, stream>>>(Whi, T64b_h, T64b_l, deg,
                                             F96a, 64, 0, F96b, 64, 0, nullptr, T64a_h, T64a_l, 0, 64);
    apply_fused<64><<<gA, b512, 0, stream>>>(Whi, T64a_h, T64a_l, deg,
                                             F96b, 64, 0, F96a, 64, 0, nullptr, T64b_h, T64b_l, 0, 64);
    apply_fused<64><<<gA, b512, 0, stream>>>(Whi, T64b_h, T64b_l, deg,
                                             F96a, 64, 0, Z8, 64, 0, nullptr, nullptr, nullptr, 0, 64);

    hipMemsetAsync(out, 0, (size_t)NPAIR * 224 * sizeof(float), stream);
    pool_kernel<<<dim3(7, NPAIR, 8), dim3(32, 8), 0, stream>>>(X, M0, M2p, M4f, Z8, out);
}